// Round 10
// baseline (510.252 us; speedup 1.0000x reference)
//
#include <hip/hip_runtime.h>
#include <cstdint>
#include <cstddef>

typedef unsigned short u16;
typedef unsigned int u32;
typedef short bf16x8 __attribute__((ext_vector_type(8)));
typedef float f32x4 __attribute__((ext_vector_type(4)));
typedef float f32x16 __attribute__((ext_vector_type(16)));
typedef u16 u16x4 __attribute__((ext_vector_type(4)));

__device__ __forceinline__ u16 f2bf(float f) {
  u32 u = __float_as_uint(f);
  return (u16)((u + 0x7FFFu + ((u >> 16) & 1u)) >> 16);
}
__device__ __forceinline__ float bf2f(u16 h) {
  return __uint_as_float(((u32)h) << 16);
}
__device__ __forceinline__ u32 cvtpk(float lo, float hi) {
  u32 r;
  asm("v_cvt_pk_bf16_f32 %0, %1, %2" : "=v"(r) : "v"(lo), "v"(hi));
  return r;
}
__device__ __forceinline__ float exp2a(float x) {
  float r;
  asm("v_exp_f32 %0, %1" : "=v"(r) : "v"(x));
  return r;
}

__device__ __forceinline__ void gload_lds16(const void* g, void* l) {
  __builtin_amdgcn_global_load_lds((const __attribute__((address_space(1))) u32*)g,
                                   (__attribute__((address_space(3))) u32*)l, 16, 0, 0);
}

// ---------------- weight cast fp32 -> bf16 ----------------
__global__ __launch_bounds__(256) void castw(const float* __restrict__ src,
                                             u16* __restrict__ dst, int n4) {
  int i = blockIdx.x * 256 + threadIdx.x;
  if (i < n4) {
    float4 v = ((const float4*)src)[i];
    u16x4 r;
    r.x = f2bf(v.x); r.y = f2bf(v.y); r.z = f2bf(v.z); r.w = f2bf(v.w);
    ((u16x4*)dst)[i] = r;
  }
}

// ---------------- RMSNorm: fp32 [rows,1024] -> bf16 ----------------
__global__ __launch_bounds__(256) void rmsnorm_k(const float* __restrict__ x,
                                                 const float* __restrict__ gamma,
                                                 u16* __restrict__ o) {
  const int row = blockIdx.x;
  const int t = threadIdx.x;
  float4 v = ((const float4*)(x + (size_t)row * 1024))[t];
  float ss = v.x * v.x + v.y * v.y + v.z * v.z + v.w * v.w;
  #pragma unroll
  for (int m = 1; m < 64; m <<= 1) ss += __shfl_xor(ss, m);
  __shared__ float wsum[4];
  if ((t & 63) == 0) wsum[t >> 6] = ss;
  __syncthreads();
  float tot = wsum[0] + wsum[1] + wsum[2] + wsum[3];
  float inv = rsqrtf(tot * (1.0f / 1024.0f) + 1e-5f);
  float4 g = ((const float4*)gamma)[t];
  u16x4 r;
  r.x = f2bf(v.x * inv * g.x);
  r.y = f2bf(v.y * inv * g.y);
  r.z = f2bf(v.z * inv * g.z);
  r.w = f2bf(v.w * inv * g.w);
  ((u16x4*)(o + (size_t)row * 1024))[t] = r;
}

// ---- shared epilogue helpers (indices identical across GEMM variants) ----

// ========== 128x128 BK=64 single-buffer GEMM (baseline, 4 blocks/CU) =======
template <int EPI>
__global__ __launch_bounds__(256, 4)
void gemm128(const u16* __restrict__ A, const u16* __restrict__ B,
             void* out, const void* ep, int M, int N, int KLOOP, int KS,
             float scale, int ncut) {
  __shared__ u16 smem[2][8192];
  u16* const sA = smem[0];
  u16* const sB = smem[1];

  const int tid = threadIdx.x;
  const int lane = tid & 63;
  const int w = tid >> 6;
  const int wr = w >> 1, wc = w & 1;
  const int lr = lane & 15, lk = lane >> 4;

  A += (size_t)blockIdx.z * KLOOP;
  B += (size_t)blockIdx.z * KLOOP;

  const int nx = gridDim.x;
  const int nwg = nx * gridDim.y;
  const int flat = blockIdx.y * nx + blockIdx.x;
  const int qq = nwg >> 3, rr = nwg & 7;
  const int xcd = flat & 7, off = flat >> 3;
  const int swz = (xcd < rr ? xcd * (qq + 1) : rr * (qq + 1) + (xcd - rr) * qq) + off;
  const int sr = nx * 8;
  const int g8 = swz / sr, rem = swz % sr;
  const int m0 = (g8 * 8 + (rem & 7)) * 128;
  const int n0 = (rem >> 3) * 128;

  f32x4 acc[4][4];
  #pragma unroll
  for (int i = 0; i < 4; i++)
    #pragma unroll
    for (int j = 0; j < 4; j++) acc[i][j] = (f32x4){0.f, 0.f, 0.f, 0.f};

  for (int kt = 0; kt < KLOOP; kt += 64) {
    __syncthreads();
    #pragma unroll
    for (int r = 0; r < 4; r++) {
      const int q = r * 256 + tid;
      const int row = q >> 3;
      const int cs = (q & 7) ^ (row & 7);
      gload_lds16(A + (size_t)(m0 + row) * KS + kt + cs * 8, (char*)sA + q * 16);
      gload_lds16(B + (size_t)(n0 + row) * KS + kt + cs * 8, (char*)sB + q * 16);
    }
    __syncthreads();
    #pragma unroll
    for (int kk = 0; kk < 2; kk++) {
      bf16x8 a_[4], b_[4];
      #pragma unroll
      for (int i = 0; i < 4; i++)
        a_[i] = *(const bf16x8*)&sA[(wr * 64 + i * 16 + lr) * 64 +
                                    (((kk * 4 + lk) ^ (lr & 7)) * 8)];
      #pragma unroll
      for (int j = 0; j < 4; j++)
        b_[j] = *(const bf16x8*)&sB[(wc * 64 + j * 16 + lr) * 64 +
                                    (((kk * 4 + lk) ^ (lr & 7)) * 8)];
      #pragma unroll
      for (int i = 0; i < 4; i++)
        #pragma unroll
        for (int j = 0; j < 4; j++)
          acc[i][j] = __builtin_amdgcn_mfma_f32_16x16x32_bf16(a_[i], b_[j], acc[i][j], 0, 0, 0);
    }
  }

  if constexpr (EPI == 1 || EPI == 3) {
    #pragma unroll
    for (int i = 0; i < 4; i++)
      #pragma unroll
      for (int j = 0; j < 4; j++)
        #pragma unroll
        for (int r = 0; r < 4; r++) {
          const int grow = m0 + wr * 64 + i * 16 + lk * 4 + r;
          const int gcol = n0 + wc * 64 + j * 16 + lr;
          const size_t idx = (size_t)grow * N + gcol;
          if (EPI == 1) ((float*)out)[idx] = ((const float*)ep)[idx] + acc[i][j][r];
          else          unsafeAtomicAdd((float*)out + idx, acc[i][j][r]);
        }
  } else {
    u16* const smC = smem[0];
    const float s = (EPI == 0 && n0 < ncut) ? scale : 1.0f;
    __syncthreads();
    #pragma unroll
    for (int i = 0; i < 4; i++)
      #pragma unroll
      for (int j = 0; j < 4; j++)
        #pragma unroll
        for (int r = 0; r < 4; r++) {
          const int row = wr * 64 + i * 16 + lk * 4 + r;
          const int col = wc * 64 + j * 16 + lr;
          smC[row * 128 + (col ^ ((row & 7) << 3))] = f2bf(acc[i][j][r] * s);
        }
    __syncthreads();
    #pragma unroll
    for (int it = 0; it < 8; it++) {
      const int fl = it * 256 + tid;
      const int row = fl >> 4;
      const int ch = fl & 15;
      bf16x8 cv = *(const bf16x8*)&smC[row * 128 + ((ch ^ (row & 7)) * 8)];
      const size_t gidx = (size_t)(m0 + row) * N + n0 + ch * 8;
      if (EPI == 0) {
        *(bf16x8*)((u16*)out + gidx) = cv;
      } else {
        bf16x8 gv = *(const bf16x8*)((const u16*)ep + gidx);
        bf16x8 ov;
        #pragma unroll
        for (int k = 0; k < 8; k++) {
          float g = bf2f((u16)gv[k]);
          float sg = g / (1.f + __expf(-g));
          ov[k] = (short)f2bf(sg * bf2f((u16)cv[k]));
        }
        *(bf16x8*)((u16*)out + gidx) = ov;
      }
    }
  }
}

// ========== A/B variant: BK=64 DOUBLE-buffered (64KB LDS, 2 blocks/CU) =====
// Prefetch-first, one __syncthreads per K-tile (drain hidden under compute).
template <int EPI>
__global__ __launch_bounds__(256, 2)
void gemm128db(const u16* __restrict__ A, const u16* __restrict__ B,
               void* out, const void* ep, int M, int N, int KLOOP, int KS,
               float scale, int ncut) {
  __shared__ u16 sA[2][8192];
  __shared__ u16 sB[2][8192];

  const int tid = threadIdx.x;
  const int lane = tid & 63;
  const int w = tid >> 6;
  const int wr = w >> 1, wc = w & 1;
  const int lr = lane & 15, lk = lane >> 4;

  A += (size_t)blockIdx.z * KLOOP;
  B += (size_t)blockIdx.z * KLOOP;

  const int nx = gridDim.x;
  const int nwg = nx * gridDim.y;
  const int flat = blockIdx.y * nx + blockIdx.x;
  const int qq = nwg >> 3, rr = nwg & 7;
  const int xcd = flat & 7, off = flat >> 3;
  const int swz = (xcd < rr ? xcd * (qq + 1) : rr * (qq + 1) + (xcd - rr) * qq) + off;
  const int sr = nx * 8;
  const int g8 = swz / sr, rem = swz % sr;
  const int m0 = (g8 * 8 + (rem & 7)) * 128;
  const int n0 = (rem >> 3) * 128;

  f32x4 acc[4][4];
  #pragma unroll
  for (int i = 0; i < 4; i++)
    #pragma unroll
    for (int j = 0; j < 4; j++) acc[i][j] = (f32x4){0.f, 0.f, 0.f, 0.f};

  #define STAGE128(BUF, KT)                                                       \
    _Pragma("unroll")                                                             \
    for (int r = 0; r < 4; r++) {                                                 \
      const int q = r * 256 + tid;                                                \
      const int row = q >> 3;                                                     \
      const int cs = (q & 7) ^ (row & 7);                                         \
      gload_lds16(A + (size_t)(m0 + row) * KS + (KT) + cs * 8,                    \
                  (char*)sA[BUF] + q * 16);                                       \
      gload_lds16(B + (size_t)(n0 + row) * KS + (KT) + cs * 8,                    \
                  (char*)sB[BUF] + q * 16);                                       \
    }

  const int NT = KLOOP >> 6;
  STAGE128(0, 0)
  __syncthreads();

  for (int W = 0; W < NT; ++W) {
    const int buf = W & 1;
    if (W + 1 < NT) { STAGE128(buf ^ 1, (W + 1) << 6) }
    #pragma unroll
    for (int kk = 0; kk < 2; kk++) {
      bf16x8 a_[4], b_[4];
      #pragma unroll
      for (int i = 0; i < 4; i++)
        a_[i] = *(const bf16x8*)&sA[buf][(wr * 64 + i * 16 + lr) * 64 +
                                        (((kk * 4 + lk) ^ (lr & 7)) * 8)];
      #pragma unroll
      for (int j = 0; j < 4; j++)
        b_[j] = *(const bf16x8*)&sB[buf][(wc * 64 + j * 16 + lr) * 64 +
                                         (((kk * 4 + lk) ^ (lr & 7)) * 8)];
      #pragma unroll
      for (int i = 0; i < 4; i++)
        #pragma unroll
        for (int j = 0; j < 4; j++)
          acc[i][j] = __builtin_amdgcn_mfma_f32_16x16x32_bf16(a_[i], b_[j], acc[i][j], 0, 0, 0);
    }
    __syncthreads();   // drains prefetch (mostly landed) + read完
  }
  #undef STAGE128

  if constexpr (EPI == 1 || EPI == 3) {
    #pragma unroll
    for (int i = 0; i < 4; i++)
      #pragma unroll
      for (int j = 0; j < 4; j++)
        #pragma unroll
        for (int r = 0; r < 4; r++) {
          const int grow = m0 + wr * 64 + i * 16 + lk * 4 + r;
          const int gcol = n0 + wc * 64 + j * 16 + lr;
          const size_t idx = (size_t)grow * N + gcol;
          if (EPI == 1) ((float*)out)[idx] = ((const float*)ep)[idx] + acc[i][j][r];
          else          unsafeAtomicAdd((float*)out + idx, acc[i][j][r]);
        }
  } else {
    u16* const smC = sA[0];
    const float s = (EPI == 0 && n0 < ncut) ? scale : 1.0f;
    #pragma unroll
    for (int i = 0; i < 4; i++)
      #pragma unroll
      for (int j = 0; j < 4; j++)
        #pragma unroll
        for (int r = 0; r < 4; r++) {
          const int row = wr * 64 + i * 16 + lk * 4 + r;
          const int col = wc * 64 + j * 16 + lr;
          smC[row * 128 + (col ^ ((row & 7) << 3))] = f2bf(acc[i][j][r] * s);
        }
    __syncthreads();
    #pragma unroll
    for (int it = 0; it < 8; it++) {
      const int fl = it * 256 + tid;
      const int row = fl >> 4;
      const int ch = fl & 15;
      bf16x8 cv = *(const bf16x8*)&smC[row * 128 + ((ch ^ (row & 7)) * 8)];
      const size_t gidx = (size_t)(m0 + row) * N + n0 + ch * 8;
      if (EPI == 0) {
        *(bf16x8*)((u16*)out + gidx) = cv;
      } else {
        bf16x8 gv = *(const bf16x8*)((const u16*)ep + gidx);
        bf16x8 ov;
        #pragma unroll
        for (int k = 0; k < 8; k++) {
          float g = bf2f((u16)gv[k]);
          float sg = g / (1.f + __expf(-g));
          ov[k] = (short)f2bf(sg * bf2f((u16)cv[k]));
        }
        *(bf16x8*)((u16*)out + gidx) = ov;
      }
    }
  }
}

// ---------------- V transpose from packed qkv: -> vt[bh=64][d=64][s=2048] ----
__global__ __launch_bounds__(256) void vtrans(const u16* __restrict__ qkv,
                                              u16* __restrict__ vt) {
  __shared__ u16 T[64][72];
  const int t = threadIdx.x;
  const int s0 = blockIdx.x * 64;
  const int h = blockIdx.y;
  const int b = blockIdx.z;
  const int sl = t >> 2, dl = (t & 3) * 16;
  const u16* src = qkv + ((size_t)(b * 2048 + s0 + sl)) * 3072 + 2048 + h * 64 + dl;
  bf16x8 v0 = *(const bf16x8*)src;
  bf16x8 v1 = *(const bf16x8*)(src + 8);
  #pragma unroll
  for (int j = 0; j < 8; j++) T[dl + j][sl] = (u16)v0[j];
  #pragma unroll
  for (int j = 0; j < 8; j++) T[dl + 8 + j][sl] = (u16)v1[j];
  __syncthreads();
  const int dl2 = t >> 2, sl2 = (t & 3) * 16;
  u16* dst = vt + ((size_t)((b * 16 + h) * 64 + dl2)) * 2048 + s0 + sl2;
  *(bf16x8*)dst = *(const bf16x8*)&T[dl2][sl2];
  *(bf16x8*)(dst + 8) = *(const bf16x8*)&T[dl2][sl2 + 8];
}

// ---------------- causal flash attention v4 (K/V double-buffered) ----------
__global__ __launch_bounds__(256, 2)
void attn_fwd4(const u16* __restrict__ qkv, const u16* __restrict__ vt,
               u16* __restrict__ o) {
  __shared__ u16 sm[16384];   // K0|K1|V0|V1 (4KB elems each); bounce reuses
  const int tid = threadIdx.x;
  const int lane = tid & 63;
  const int w = tid >> 6;
  const int hi = lane >> 5;
  const int ln = lane & 31;

  const int bh = blockIdx.x;
  const int pair = blockIdx.y;
  const int b = bh >> 4, h = bh & 15;

  #define ATTN_STAGE(BUF, KB)                                                         \
    _Pragma("unroll")                                                                 \
    for (int r = 0; r < 2; r++) {                                                     \
      const int cb = w * 128 + r * 64;                                                \
      const int ci = cb + lane;                                                       \
      {                                                                               \
        const int key = ci >> 3, gch = (ci & 7) ^ (key & 7);                          \
        const u16* src = qkv + ((size_t)(b * 2048 + (KB) * 64 + key)) * 3072 + 1024 + \
                         h * 64 + gch * 8;                                            \
        gload_lds16(src, (char*)(sm + (BUF) * 4096) + cb * 16);                       \
      }                                                                               \
      {                                                                               \
        const int d = ci >> 3, gch = (ci & 7) ^ (d & 7);                              \
        const u16* src = vt + ((size_t)(bh * 64 + d)) * 2048 + (KB) * 64 + gch * 8;   \
        gload_lds16(src, (char*)(sm + 8192 + (BUF) * 4096) + cb * 16);                \
      }                                                                               \
    }

  #pragma unroll 1
  for (int phase = 0; phase < 2; ++phase) {
    const int qt = phase ? (15 - pair) : pair;
    const int qbase = qt * 128;
    const int qw0 = qbase + w * 32;
    const int qglob = qw0 + ln;
    const int nkb = qt * 2 + 2;

    bf16x8 qf[4];
    {
      const u16* qp = qkv + ((size_t)(b * 2048 + qw0 + ln)) * 3072 + h * 64 + hi * 8;
      #pragma unroll
      for (int c = 0; c < 4; c++) qf[c] = *(const bf16x8*)(qp + c * 16);
    }

    f32x16 accO[2];
    #pragma unroll
    for (int i = 0; i < 2; i++)
      #pragma unroll
      for (int r = 0; r < 16; r++) accO[i][r] = 0.f;
    float mrun = -1e30f, lsum = 0.f;

    ATTN_STAGE(0, 0)
    __syncthreads();

    for (int kb = 0; kb < nkb; kb++) {
      const int kbase = kb * 64;
      const int buf = kb & 1;
      if (kb + 1 < nkb) { ATTN_STAGE(buf ^ 1, kb + 1) }
      const u16* smK = sm + buf * 4096;
      const u16* smV = sm + 8192 + buf * 4096;

      if (kbase <= qw0 + 31) {
        f32x16 st[2];
        #pragma unroll
        for (int kt = 0; kt < 2; kt++) {
          #pragma unroll
          for (int r = 0; r < 16; r++) st[kt][r] = 0.f;
        }
        __builtin_amdgcn_s_setprio(1);
        #pragma unroll
        for (int kt = 0; kt < 2; kt++)
          #pragma unroll
          for (int c = 0; c < 4; c++) {
            const int row = kt * 32 + ln;
            const int sch = (c * 2 + hi) ^ (ln & 7);
            bf16x8 kf = *(const bf16x8*)((const char*)smK + row * 128 + sch * 16);
            st[kt] = __builtin_amdgcn_mfma_f32_32x32x16_bf16(kf, qf[c], st[kt], 0, 0, 0);
          }
        __builtin_amdgcn_s_setprio(0);
        if (kbase + 63 > qw0) {
          #pragma unroll
          for (int kt = 0; kt < 2; kt++)
            #pragma unroll
            for (int r = 0; r < 16; r++) {
              const int kk = kbase + kt * 32 + (r & 3) + 8 * (r >> 2) + 4 * hi;
              if (kk > qglob) st[kt][r] = -1e30f;
            }
        }
        float t16[16];
        #pragma unroll
        for (int i = 0; i < 16; i++) t16[i] = fmaxf(st[0][i], st[1][i]);
        #pragma unroll
        for (int s = 8; s > 0; s >>= 1)
          #pragma unroll
          for (int i = 0; i < 8; i++)
            if (i < s) t16[i] = fmaxf(t16[i], t16[i + s]);
        float pm = t16[0];
        pm = fmaxf(pm, __shfl_xor(pm, 32));
        if (!__all(pm - mrun <= 8.f)) {
          const float mnew = fmaxf(mrun, pm);
          const float alpha = exp2a(mrun - mnew);
          lsum *= alpha;
          accO[0] *= alpha;
          accO[1] *= alpha;
          mrun = mnew;
        }
        #pragma unroll
        for (int kt = 0; kt < 2; kt++)
          #pragma unroll
          for (int r = 0; r < 16; r++) st[kt][r] = exp2a(st[kt][r] - mrun);
        float s16[16];
        #pragma unroll
        for (int i = 0; i < 16; i++) s16[i] = st[0][i] + st[1][i];
        #pragma unroll
        for (int s = 8; s > 0; s >>= 1)
          #pragma unroll
          for (int i = 0; i < 8; i++)
            if (i < s) s16[i] = s16[i] + s16[i + s];
        float ps = s16[0];
        ps += __shfl_xor(ps, 32);
        lsum += ps;

        #pragma unroll
        for (int kt = 0; kt < 2; kt++) {
          u32 pw[8], px[8];
          #pragma unroll
          for (int i = 0; i < 8; i++) pw[i] = cvtpk(st[kt][2 * i], st[kt][2 * i + 1]);
          #pragma unroll
          for (int i = 0; i < 8; i++) px[i] = (u32)__shfl_xor((int)pw[i], 32);
          union { u32 wd[4]; bf16x8 v; } f0, f1;
          f0.wd[0] = hi ? px[2] : pw[0];
          f0.wd[1] = hi ? px[3] : pw[1];
          f0.wd[2] = hi ? pw[2] : px[0];
          f0.wd[3] = hi ? pw[3] : px[1];
          f1.wd[0] = hi ? px[6] : pw[4];
          f1.wd[1] = hi ? px[7] : pw[5];
          f1.wd[2] = hi ? pw[6] : px[4];
          f1.wd[3] = hi ? pw[7] : px[5];
          __builtin_amdgcn_s_setprio(1);
          #pragma unroll
          for (int d0 = 0; d0 < 2; d0++) {
            #pragma unroll
            for (int kc = 0; kc < 2; kc++) {
              const int drow = d0 * 32 + ln;
              const int sch = (kt * 4 + kc * 2 + hi) ^ (ln & 7);
              bf16x8 vf = *(const bf16x8*)((const char*)smV + drow * 128 + sch * 16);
              accO[d0] = __builtin_amdgcn_mfma_f32_32x32x16_bf16(vf, kc ? f1.v : f0.v,
                                                                 accO[d0], 0, 0, 0);
            }
          }
          __builtin_amdgcn_s_setprio(0);
        }
      }
      __syncthreads();
    }

    const float inv = 1.0f / lsum;
    #pragma unroll
    for (int d0 = 0; d0 < 2; d0++)
      #pragma unroll
      for (int r = 0; r < 16; r++) {
        const int d = d0 * 32 + (r & 3) + 8 * (r >> 2) + 4 * hi;
        sm[(w * 32 + ln) * 72 + d] = f2bf(accO[d0][r] * inv);
      }
    __syncthreads();
    const int ql = tid >> 1, dh = (tid & 1) * 32;
    const u16* srcp = &sm[ql * 72 + dh];
    u16* dst = o + ((size_t)(b * 2048 + qbase + ql)) * 1024 + h * 64 + dh;
    #pragma unroll
    for (int j = 0; j < 4; j++)
      *(bf16x8*)(dst + j * 8) = *(const bf16x8*)(srcp + j * 8);
    __syncthreads();
  }
  #undef ATTN_STAGE
}

// ---------------- host ----------------
extern "C" void kernel_launch(void* const* d_in, const int* in_sizes, int n_in,
                              void* d_out, int out_size, void* d_ws, size_t ws_size,
                              hipStream_t stream) {
  const float* x      = (const float*)d_in[0];
  const float* W_q    = (const float*)d_in[1];
  const float* W_k    = (const float*)d_in[2];
  const float* W_v    = (const float*)d_in[3];
  const float* W_o    = (const float*)d_in[4];
  const float* gamma1 = (const float*)d_in[5];
  const float* gamma2 = (const float*)d_in[6];
  const float* W1     = (const float*)d_in[7];
  const float* W2     = (const float*)d_in[8];
  const float* W3     = (const float*)d_in[9];

  char* ws = (char*)d_ws;
  const size_t MB = 1ull << 20;
  u16* qkvw  = (u16*)(ws + 0 * MB);
  u16* Wo_b  = (u16*)(ws + 6 * MB);
  u16* W1_b  = (u16*)(ws + 8 * MB);
  u16* W3_b  = (u16*)(ws + 16 * MB);
  u16* W2_b  = (u16*)(ws + 24 * MB);
  u16* xn    = (u16*)(ws + 32 * MB);
  u16* qkvb  = (u16*)(ws + 48 * MB);
  u16* attnb = (u16*)(ws + 96 * MB);
  u16* vtb   = (u16*)(ws + 112 * MB);
  u16* gbuf  = (u16*)(ws + 112 * MB);
  u16* hbuf  = (u16*)(ws + 48 * MB);
  float* x1  = (float*)d_out;

  castw<<<1024, 256, 0, stream>>>(W_q, qkvw, 262144);
  castw<<<1024, 256, 0, stream>>>(W_k, qkvw + 1024 * 1024, 262144);
  castw<<<1024, 256, 0, stream>>>(W_v, qkvw + 2048 * 1024, 262144);
  castw<<<1024, 256, 0, stream>>>(W_o, Wo_b, 262144);
  castw<<<4096, 256, 0, stream>>>(W1, W1_b, 1048576);
  castw<<<4096, 256, 0, stream>>>(W3, W3_b, 1048576);
  castw<<<4096, 256, 0, stream>>>(W2, W2_b, 1048576);

  rmsnorm_k<<<8192, 256, 0, stream>>>(x, gamma1, xn);
  gemm128<0><<<dim3(24, 64), 256, 0, stream>>>(xn, qkvw, qkvb, nullptr,
                                               8192, 3072, 1024, 1024,
                                               0.125f * 1.44269504f, 1024);
  vtrans<<<dim3(32, 16, 4), 256, 0, stream>>>(qkvb, vtb);
  attn_fwd4<<<dim3(64, 8), 256, 0, stream>>>(qkvb, vtb, attnb);
  gemm128<1><<<dim3(8, 64), 256, 0, stream>>>(attnb, Wo_b, x1, x,
                                              8192, 1024, 1024, 1024, 1.0f, 0);

  rmsnorm_k<<<8192, 256, 0, stream>>>(x1, gamma2, xn);
  // A/B: gate uses DOUBLE-buffered variant, up keeps single-buffer baseline
  gemm128db<0><<<dim3(32, 64), 256, 0, stream>>>(xn, W1_b, gbuf, nullptr,
                                                 8192, 4096, 1024, 1024, 1.0f, 0);
  gemm128<2><<<dim3(32, 64), 256, 0, stream>>>(xn, W3_b, hbuf, gbuf,
                                               8192, 4096, 1024, 1024, 1.0f, 0);
  gemm128<3><<<dim3(8, 64, 2), 256, 0, stream>>>(hbuf, W2_b, (float*)d_out, nullptr,
                                                 8192, 1024, 2048, 4096, 1.0f, 0);
}

// Round 11
// 475.940 us; speedup vs baseline: 1.0721x; 1.0721x over previous
//
#include <hip/hip_runtime.h>
#include <cstdint>
#include <cstddef>

typedef unsigned short u16;
typedef unsigned int u32;
typedef short bf16x8 __attribute__((ext_vector_type(8)));
typedef float f32x4 __attribute__((ext_vector_type(4)));
typedef float f32x16 __attribute__((ext_vector_type(16)));
typedef u16 u16x4 __attribute__((ext_vector_type(4)));

__device__ __forceinline__ u16 f2bf(float f) {
  u32 u = __float_as_uint(f);
  return (u16)((u + 0x7FFFu + ((u >> 16) & 1u)) >> 16);
}
__device__ __forceinline__ float bf2f(u16 h) {
  return __uint_as_float(((u32)h) << 16);
}
__device__ __forceinline__ u32 cvtpk(float lo, float hi) {
  u32 r;
  asm("v_cvt_pk_bf16_f32 %0, %1, %2" : "=v"(r) : "v"(lo), "v"(hi));
  return r;
}
__device__ __forceinline__ float exp2a(float x) {
  float r;
  asm("v_exp_f32 %0, %1" : "=v"(r) : "v"(x));
  return r;
}

__device__ __forceinline__ void gload_lds16(const void* g, void* l) {
  __builtin_amdgcn_global_load_lds((const __attribute__((address_space(1))) u32*)g,
                                   (__attribute__((address_space(3))) u32*)l, 16, 0, 0);
}

// ---------------- weight cast fp32 -> bf16 ----------------
__global__ __launch_bounds__(256) void castw(const float* __restrict__ src,
                                             u16* __restrict__ dst, int n4) {
  int i = blockIdx.x * 256 + threadIdx.x;
  if (i < n4) {
    float4 v = ((const float4*)src)[i];
    u16x4 r;
    r.x = f2bf(v.x); r.y = f2bf(v.y); r.z = f2bf(v.z); r.w = f2bf(v.w);
    ((u16x4*)dst)[i] = r;
  }
}

// cast + interleave pack: W1/W3 [4096][1024] -> W13 [8192][1024],
// group g: rows g*128+0..63 = W1 rows g*64..; +64..127 = W3 rows g*64..
__global__ __launch_bounds__(256) void castw_pack(const float* __restrict__ src,
                                                  u16* __restrict__ dst, int half) {
  int i = blockIdx.x * 256 + threadIdx.x;    // over 1048576 float4
  float4 v = ((const float4*)src)[i];
  const int n = i >> 8;                      // src row
  const int c4 = i & 255;
  const int orow = ((n >> 6) << 7) + (half << 6) + (n & 63);
  u16x4 r;
  r.x = f2bf(v.x); r.y = f2bf(v.y); r.z = f2bf(v.z); r.w = f2bf(v.w);
  ((u16x4*)dst)[orow * 256 + c4] = r;
}

// ---------------- RMSNorm: fp32 [rows,1024] -> bf16 ----------------
__global__ __launch_bounds__(256) void rmsnorm_k(const float* __restrict__ x,
                                                 const float* __restrict__ gamma,
                                                 u16* __restrict__ o) {
  const int row = blockIdx.x;
  const int t = threadIdx.x;
  float4 v = ((const float4*)(x + (size_t)row * 1024))[t];
  float ss = v.x * v.x + v.y * v.y + v.z * v.z + v.w * v.w;
  #pragma unroll
  for (int m = 1; m < 64; m <<= 1) ss += __shfl_xor(ss, m);
  __shared__ float wsum[4];
  if ((t & 63) == 0) wsum[t >> 6] = ss;
  __syncthreads();
  float tot = wsum[0] + wsum[1] + wsum[2] + wsum[3];
  float inv = rsqrtf(tot * (1.0f / 1024.0f) + 1e-5f);
  float4 g = ((const float4*)gamma)[t];
  u16x4 r;
  r.x = f2bf(v.x * inv * g.x);
  r.y = f2bf(v.y * inv * g.y);
  r.z = f2bf(v.z * inv * g.z);
  r.w = f2bf(v.w * inv * g.w);
  ((u16x4*)(o + (size_t)row * 1024))[t] = r;
}

// ========== 128x128 BK=64 single-buffer GEMM (4 blocks/CU) ==================
// EPI 0: bf16 = acc * (n0<ncut?scale:1)     (LDS-bounce, coalesced)
// EPI 1: fp32 = acc + ep_fp32[idx]
// EPI 3: fp32 unsafeAtomicAdd(out+idx, acc) (split-K via blockIdx.z)
// EPI 4: fused SwiGLU: C tile = [gate cols 0-63 | up cols 64-127] of one
//        ff-group; write silu(g)*u to out[M][N] at col (n0>>1)+c  (N=out width)
template <int EPI>
__global__ __launch_bounds__(256, 4)
void gemm128(const u16* __restrict__ A, const u16* __restrict__ B,
             void* out, const void* ep, int M, int N, int KLOOP, int KS,
             float scale, int ncut) {
  __shared__ u16 smem[2][8192];
  u16* const sA = smem[0];
  u16* const sB = smem[1];

  const int tid = threadIdx.x;
  const int lane = tid & 63;
  const int w = tid >> 6;
  const int wr = w >> 1, wc = w & 1;
  const int lr = lane & 15, lk = lane >> 4;

  A += (size_t)blockIdx.z * KLOOP;
  B += (size_t)blockIdx.z * KLOOP;

  const int nx = gridDim.x;
  const int nwg = nx * gridDim.y;
  const int flat = blockIdx.y * nx + blockIdx.x;
  const int qq = nwg >> 3, rr = nwg & 7;
  const int xcd = flat & 7, off = flat >> 3;
  const int swz = (xcd < rr ? xcd * (qq + 1) : rr * (qq + 1) + (xcd - rr) * qq) + off;
  const int sr = nx * 8;
  const int g8 = swz / sr, rem = swz % sr;
  const int m0 = (g8 * 8 + (rem & 7)) * 128;
  const int n0 = (rem >> 3) * 128;

  f32x4 acc[4][4];
  #pragma unroll
  for (int i = 0; i < 4; i++)
    #pragma unroll
    for (int j = 0; j < 4; j++) acc[i][j] = (f32x4){0.f, 0.f, 0.f, 0.f};

  for (int kt = 0; kt < KLOOP; kt += 64) {
    __syncthreads();
    #pragma unroll
    for (int r = 0; r < 4; r++) {
      const int q = r * 256 + tid;
      const int row = q >> 3;
      const int cs = (q & 7) ^ (row & 7);
      gload_lds16(A + (size_t)(m0 + row) * KS + kt + cs * 8, (char*)sA + q * 16);
      gload_lds16(B + (size_t)(n0 + row) * KS + kt + cs * 8, (char*)sB + q * 16);
    }
    __syncthreads();
    #pragma unroll
    for (int kk = 0; kk < 2; kk++) {
      bf16x8 a_[4], b_[4];
      #pragma unroll
      for (int i = 0; i < 4; i++)
        a_[i] = *(const bf16x8*)&sA[(wr * 64 + i * 16 + lr) * 64 +
                                    (((kk * 4 + lk) ^ (lr & 7)) * 8)];
      #pragma unroll
      for (int j = 0; j < 4; j++)
        b_[j] = *(const bf16x8*)&sB[(wc * 64 + j * 16 + lr) * 64 +
                                    (((kk * 4 + lk) ^ (lr & 7)) * 8)];
      #pragma unroll
      for (int i = 0; i < 4; i++)
        #pragma unroll
        for (int j = 0; j < 4; j++)
          acc[i][j] = __builtin_amdgcn_mfma_f32_16x16x32_bf16(a_[i], b_[j], acc[i][j], 0, 0, 0);
    }
  }

  if constexpr (EPI == 1 || EPI == 3) {
    #pragma unroll
    for (int i = 0; i < 4; i++)
      #pragma unroll
      for (int j = 0; j < 4; j++)
        #pragma unroll
        for (int r = 0; r < 4; r++) {
          const int grow = m0 + wr * 64 + i * 16 + lk * 4 + r;
          const int gcol = n0 + wc * 64 + j * 16 + lr;
          const size_t idx = (size_t)grow * N + gcol;
          if (EPI == 1) ((float*)out)[idx] = ((const float*)ep)[idx] + acc[i][j][r];
          else          unsafeAtomicAdd((float*)out + idx, acc[i][j][r]);
        }
  } else {
    u16* const smC = smem[0];
    const float s = (EPI == 0 && n0 < ncut) ? scale : 1.0f;
    __syncthreads();
    #pragma unroll
    for (int i = 0; i < 4; i++)
      #pragma unroll
      for (int j = 0; j < 4; j++)
        #pragma unroll
        for (int r = 0; r < 4; r++) {
          const int row = wr * 64 + i * 16 + lk * 4 + r;
          const int col = wc * 64 + j * 16 + lr;
          smC[row * 128 + (col ^ ((row & 7) << 3))] = f2bf(acc[i][j][r] * s);
        }
    __syncthreads();
    if constexpr (EPI == 4) {
      // silu(gate) * up in-LDS; 1024 chunks = 128 rows x 8 out-chunks
      #pragma unroll
      for (int it = 0; it < 4; it++) {
        const int fl = it * 256 + tid;
        const int row = fl >> 3;
        const int ch = fl & 7;
        bf16x8 gvv = *(const bf16x8*)&smC[row * 128 + ((ch ^ (row & 7)) * 8)];
        bf16x8 uvv = *(const bf16x8*)&smC[row * 128 + (((ch + 8) ^ (row & 7)) * 8)];
        bf16x8 ov;
        #pragma unroll
        for (int k = 0; k < 8; k++) {
          float g = bf2f((u16)gvv[k]);
          float u = bf2f((u16)uvv[k]);
          float sg = g / (1.f + __expf(-g));
          ov[k] = (short)f2bf(sg * u);
        }
        *(bf16x8*)((u16*)out + (size_t)(m0 + row) * N + (n0 >> 1) + ch * 8) = ov;
      }
    } else {
      #pragma unroll
      for (int it = 0; it < 8; it++) {
        const int fl = it * 256 + tid;
        const int row = fl >> 4;
        const int ch = fl & 15;
        bf16x8 cv = *(const bf16x8*)&smC[row * 128 + ((ch ^ (row & 7)) * 8)];
        const size_t gidx = (size_t)(m0 + row) * N + n0 + ch * 8;
        *(bf16x8*)((u16*)out + gidx) = cv;
      }
    }
  }
}

// ---------------- V transpose from packed qkv: -> vt[bh=64][d=64][s=2048] ----
__global__ __launch_bounds__(256) void vtrans(const u16* __restrict__ qkv,
                                              u16* __restrict__ vt) {
  __shared__ u16 T[64][72];
  const int t = threadIdx.x;
  const int s0 = blockIdx.x * 64;
  const int h = blockIdx.y;
  const int b = blockIdx.z;
  const int sl = t >> 2, dl = (t & 3) * 16;
  const u16* src = qkv + ((size_t)(b * 2048 + s0 + sl)) * 3072 + 2048 + h * 64 + dl;
  bf16x8 v0 = *(const bf16x8*)src;
  bf16x8 v1 = *(const bf16x8*)(src + 8);
  #pragma unroll
  for (int j = 0; j < 8; j++) T[dl + j][sl] = (u16)v0[j];
  #pragma unroll
  for (int j = 0; j < 8; j++) T[dl + 8 + j][sl] = (u16)v1[j];
  __syncthreads();
  const int dl2 = t >> 2, sl2 = (t & 3) * 16;
  u16* dst = vt + ((size_t)((b * 16 + h) * 64 + dl2)) * 2048 + s0 + sl2;
  *(bf16x8*)dst = *(const bf16x8*)&T[dl2][sl2];
  *(bf16x8*)(dst + 8) = *(const bf16x8*)&T[dl2][sl2 + 8];
}

// ---------------- causal flash attention v3 (round-9 verified config) -------
__global__ __launch_bounds__(256, 2)
void attn_fwd3(const u16* __restrict__ qkv, const u16* __restrict__ vt,
               u16* __restrict__ o) {
  __shared__ u16 sm[9216];
  u16* const smK = sm;
  u16* const smV = sm + 4096;

  const int tid = threadIdx.x;
  const int lane = tid & 63;
  const int w = tid >> 6;
  const int hi = lane >> 5;
  const int ln = lane & 31;

  const int bh = blockIdx.x;
  const int pair = blockIdx.y;
  const int b = bh >> 4, h = bh & 15;

  #pragma unroll 1
  for (int phase = 0; phase < 2; ++phase) {
    const int qt = phase ? (15 - pair) : pair;
    const int qbase = qt * 128;
    const int qw0 = qbase + w * 32;
    const int qglob = qw0 + ln;
    const int nkb = qt * 2 + 2;

    bf16x8 qf[4];
    {
      const u16* qp = qkv + ((size_t)(b * 2048 + qw0 + ln)) * 3072 + h * 64 + hi * 8;
      #pragma unroll
      for (int c = 0; c < 4; c++) qf[c] = *(const bf16x8*)(qp + c * 16);
    }

    f32x16 accO[2];
    #pragma unroll
    for (int i = 0; i < 2; i++)
      #pragma unroll
      for (int r = 0; r < 16; r++) accO[i][r] = 0.f;
    float mrun = -1e30f, lsum = 0.f;

    for (int kb = 0; kb < nkb; kb++) {
      const int kbase = kb * 64;
      __syncthreads();
      #pragma unroll
      for (int r = 0; r < 2; r++) {
        const int cb = w * 128 + r * 64;
        const int ci = cb + lane;
        {
          const int key = ci >> 3, gch = (ci & 7) ^ (key & 7);
          const u16* src = qkv + ((size_t)(b * 2048 + kbase + key)) * 3072 + 1024 + h * 64 + gch * 8;
          gload_lds16(src, (char*)smK + cb * 16);
        }
        {
          const int d = ci >> 3, gch = (ci & 7) ^ (d & 7);
          const u16* src = vt + ((size_t)(bh * 64 + d)) * 2048 + kbase + gch * 8;
          gload_lds16(src, (char*)smV + cb * 16);
        }
      }
      __syncthreads();

      if (kbase <= qw0 + 31) {
        f32x16 st[2];
        #pragma unroll
        for (int kt = 0; kt < 2; kt++) {
          #pragma unroll
          for (int r = 0; r < 16; r++) st[kt][r] = 0.f;
        }
        __builtin_amdgcn_s_setprio(1);
        #pragma unroll
        for (int kt = 0; kt < 2; kt++)
          #pragma unroll
          for (int c = 0; c < 4; c++) {
            const int row = kt * 32 + ln;
            const int sch = (c * 2 + hi) ^ (ln & 7);
            bf16x8 kf = *(const bf16x8*)((const char*)smK + row * 128 + sch * 16);
            st[kt] = __builtin_amdgcn_mfma_f32_32x32x16_bf16(kf, qf[c], st[kt], 0, 0, 0);
          }
        __builtin_amdgcn_s_setprio(0);
        if (kbase + 63 > qw0) {
          #pragma unroll
          for (int kt = 0; kt < 2; kt++)
            #pragma unroll
            for (int r = 0; r < 16; r++) {
              const int kk = kbase + kt * 32 + (r & 3) + 8 * (r >> 2) + 4 * hi;
              if (kk > qglob) st[kt][r] = -1e30f;
            }
        }
        float t16[16];
        #pragma unroll
        for (int i = 0; i < 16; i++) t16[i] = fmaxf(st[0][i], st[1][i]);
        #pragma unroll
        for (int s = 8; s > 0; s >>= 1)
          #pragma unroll
          for (int i = 0; i < 8; i++)
            if (i < s) t16[i] = fmaxf(t16[i], t16[i + s]);
        float pm = t16[0];
        pm = fmaxf(pm, __shfl_xor(pm, 32));
        if (!__all(pm - mrun <= 8.f)) {
          const float mnew = fmaxf(mrun, pm);
          const float alpha = exp2a(mrun - mnew);
          lsum *= alpha;
          accO[0] *= alpha;
          accO[1] *= alpha;
          mrun = mnew;
        }
        #pragma unroll
        for (int kt = 0; kt < 2; kt++)
          #pragma unroll
          for (int r = 0; r < 16; r++) st[kt][r] = exp2a(st[kt][r] - mrun);
        float s16[16];
        #pragma unroll
        for (int i = 0; i < 16; i++) s16[i] = st[0][i] + st[1][i];
        #pragma unroll
        for (int s = 8; s > 0; s >>= 1)
          #pragma unroll
          for (int i = 0; i < 8; i++)
            if (i < s) s16[i] = s16[i] + s16[i + s];
        float ps = s16[0];
        ps += __shfl_xor(ps, 32);
        lsum += ps;

        #pragma unroll
        for (int kt = 0; kt < 2; kt++) {
          u32 pw[8], px[8];
          #pragma unroll
          for (int i = 0; i < 8; i++) pw[i] = cvtpk(st[kt][2 * i], st[kt][2 * i + 1]);
          #pragma unroll
          for (int i = 0; i < 8; i++) px[i] = (u32)__shfl_xor((int)pw[i], 32);
          union { u32 wd[4]; bf16x8 v; } f0, f1;
          f0.wd[0] = hi ? px[2] : pw[0];
          f0.wd[1] = hi ? px[3] : pw[1];
          f0.wd[2] = hi ? pw[2] : px[0];
          f0.wd[3] = hi ? pw[3] : px[1];
          f1.wd[0] = hi ? px[6] : pw[4];
          f1.wd[1] = hi ? px[7] : pw[5];
          f1.wd[2] = hi ? pw[6] : px[4];
          f1.wd[3] = hi ? pw[7] : px[5];
          __builtin_amdgcn_s_setprio(1);
          #pragma unroll
          for (int d0 = 0; d0 < 2; d0++) {
            #pragma unroll
            for (int kc = 0; kc < 2; kc++) {
              const int drow = d0 * 32 + ln;
              const int sch = (kt * 4 + kc * 2 + hi) ^ (ln & 7);
              bf16x8 vf = *(const bf16x8*)((const char*)smV + drow * 128 + sch * 16);
              accO[d0] = __builtin_amdgcn_mfma_f32_32x32x16_bf16(vf, kc ? f1.v : f0.v,
                                                                 accO[d0], 0, 0, 0);
            }
          }
          __builtin_amdgcn_s_setprio(0);
        }
      }
    }

    __syncthreads();
    const float inv = 1.0f / lsum;
    #pragma unroll
    for (int d0 = 0; d0 < 2; d0++)
      #pragma unroll
      for (int r = 0; r < 16; r++) {
        const int d = d0 * 32 + (r & 3) + 8 * (r >> 2) + 4 * hi;
        sm[(w * 32 + ln) * 72 + d] = f2bf(accO[d0][r] * inv);
      }
    __syncthreads();
    const int ql = tid >> 1, dh = (tid & 1) * 32;
    const u16* srcp = &sm[ql * 72 + dh];
    u16* dst = o + ((size_t)(b * 2048 + qbase + ql)) * 1024 + h * 64 + dh;
    #pragma unroll
    for (int j = 0; j < 4; j++)
      *(bf16x8*)(dst + j * 8) = *(const bf16x8*)(srcp + j * 8);
    __syncthreads();
  }
}

// ---------------- host ----------------
extern "C" void kernel_launch(void* const* d_in, const int* in_sizes, int n_in,
                              void* d_out, int out_size, void* d_ws, size_t ws_size,
                              hipStream_t stream) {
  const float* x      = (const float*)d_in[0];
  const float* W_q    = (const float*)d_in[1];
  const float* W_k    = (const float*)d_in[2];
  const float* W_v    = (const float*)d_in[3];
  const float* W_o    = (const float*)d_in[4];
  const float* gamma1 = (const float*)d_in[5];
  const float* gamma2 = (const float*)d_in[6];
  const float* W1     = (const float*)d_in[7];
  const float* W2     = (const float*)d_in[8];
  const float* W3     = (const float*)d_in[9];

  char* ws = (char*)d_ws;
  const size_t MB = 1ull << 20;
  u16* qkvw  = (u16*)(ws + 0 * MB);    // [3072][1024]
  u16* Wo_b  = (u16*)(ws + 6 * MB);
  u16* W13   = (u16*)(ws + 8 * MB);    // packed [8192][1024] = 16 MB
  u16* W2_b  = (u16*)(ws + 24 * MB);
  u16* xn    = (u16*)(ws + 32 * MB);
  u16* qkvb  = (u16*)(ws + 48 * MB);   // 48 MB
  u16* attnb = (u16*)(ws + 96 * MB);
  u16* vtb   = (u16*)(ws + 112 * MB);  // dead after attn
  u16* hbuf  = (u16*)(ws + 128 * MB);  // [8192][4096] = 64 MB -> 128..192
  float* x1  = (float*)d_out;

  castw<<<1024, 256, 0, stream>>>(W_q, qkvw, 262144);
  castw<<<1024, 256, 0, stream>>>(W_k, qkvw + 1024 * 1024, 262144);
  castw<<<1024, 256, 0, stream>>>(W_v, qkvw + 2048 * 1024, 262144);
  castw<<<1024, 256, 0, stream>>>(W_o, Wo_b, 262144);
  castw_pack<<<4096, 256, 0, stream>>>(W1, W13, 0);
  castw_pack<<<4096, 256, 0, stream>>>(W3, W13, 1);
  castw<<<4096, 256, 0, stream>>>(W2, W2_b, 1048576);

  rmsnorm_k<<<8192, 256, 0, stream>>>(x, gamma1, xn);
  gemm128<0><<<dim3(24, 64), 256, 0, stream>>>(xn, qkvw, qkvb, nullptr,
                                               8192, 3072, 1024, 1024,
                                               0.125f * 1.44269504f, 1024);
  vtrans<<<dim3(32, 16, 4), 256, 0, stream>>>(qkvb, vtb);
  attn_fwd3<<<dim3(64, 8), 256, 0, stream>>>(qkvb, vtb, attnb);
  gemm128<1><<<dim3(8, 64), 256, 0, stream>>>(attnb, Wo_b, x1, x,
                                              8192, 1024, 1024, 1024, 1.0f, 0);

  rmsnorm_k<<<8192, 256, 0, stream>>>(x1, gamma2, xn);
  // fused gate+up: N(B-rows)=8192, out width 4096 (hbuf)
  gemm128<4><<<dim3(64, 64), 256, 0, stream>>>(xn, W13, hbuf, nullptr,
                                               8192, 4096, 1024, 1024, 1.0f, 0);
  // down-proj: split-K=2, fp32 atomic accumulate into d_out (holds x1)
  gemm128<3><<<dim3(8, 64, 2), 256, 0, stream>>>(hbuf, W2_b, (float*)d_out, nullptr,
                                                 8192, 1024, 2048, 4096, 1.0f, 0);
}

// Round 12
// 467.779 us; speedup vs baseline: 1.0908x; 1.0174x over previous
//
#include <hip/hip_runtime.h>
#include <cstdint>
#include <cstddef>

typedef unsigned short u16;
typedef unsigned int u32;
typedef short bf16x8 __attribute__((ext_vector_type(8)));
typedef float f32x4 __attribute__((ext_vector_type(4)));
typedef float f32x16 __attribute__((ext_vector_type(16)));
typedef u16 u16x4 __attribute__((ext_vector_type(4)));

__device__ __forceinline__ u16 f2bf(float f) {
  u32 u = __float_as_uint(f);
  return (u16)((u + 0x7FFFu + ((u >> 16) & 1u)) >> 16);
}
__device__ __forceinline__ float bf2f(u16 h) {
  return __uint_as_float(((u32)h) << 16);
}
__device__ __forceinline__ u32 cvtpk(float lo, float hi) {
  u32 r;
  asm("v_cvt_pk_bf16_f32 %0, %1, %2" : "=v"(r) : "v"(lo), "v"(hi));
  return r;
}
__device__ __forceinline__ float exp2a(float x) {
  float r;
  asm("v_exp_f32 %0, %1" : "=v"(r) : "v"(x));
  return r;
}

__device__ __forceinline__ void gload_lds16(const void* g, void* l) {
  __builtin_amdgcn_global_load_lds((const __attribute__((address_space(1))) u32*)g,
                                   (__attribute__((address_space(3))) u32*)l, 16, 0, 0);
}

// ---------------- weight cast fp32 -> bf16 ----------------
__global__ __launch_bounds__(256) void castw(const float* __restrict__ src,
                                             u16* __restrict__ dst, int n4) {
  int i = blockIdx.x * 256 + threadIdx.x;
  if (i < n4) {
    float4 v = ((const float4*)src)[i];
    u16x4 r;
    r.x = f2bf(v.x); r.y = f2bf(v.y); r.z = f2bf(v.z); r.w = f2bf(v.w);
    ((u16x4*)dst)[i] = r;
  }
}

// cast + interleave pack: W1/W3 [4096][1024] -> W13 [8192][1024]
__global__ __launch_bounds__(256) void castw_pack(const float* __restrict__ src,
                                                  u16* __restrict__ dst, int half) {
  int i = blockIdx.x * 256 + threadIdx.x;
  float4 v = ((const float4*)src)[i];
  const int n = i >> 8;
  const int c4 = i & 255;
  const int orow = ((n >> 6) << 7) + (half << 6) + (n & 63);
  u16x4 r;
  r.x = f2bf(v.x); r.y = f2bf(v.y); r.z = f2bf(v.z); r.w = f2bf(v.w);
  ((u16x4*)dst)[orow * 256 + c4] = r;
}

// ---------------- RMSNorm: fp32 [rows,1024] -> bf16 ----------------
__global__ __launch_bounds__(256) void rmsnorm_k(const float* __restrict__ x,
                                                 const float* __restrict__ gamma,
                                                 u16* __restrict__ o) {
  const int row = blockIdx.x;
  const int t = threadIdx.x;
  float4 v = ((const float4*)(x + (size_t)row * 1024))[t];
  float ss = v.x * v.x + v.y * v.y + v.z * v.z + v.w * v.w;
  #pragma unroll
  for (int m = 1; m < 64; m <<= 1) ss += __shfl_xor(ss, m);
  __shared__ float wsum[4];
  if ((t & 63) == 0) wsum[t >> 6] = ss;
  __syncthreads();
  float tot = wsum[0] + wsum[1] + wsum[2] + wsum[3];
  float inv = rsqrtf(tot * (1.0f / 1024.0f) + 1e-5f);
  float4 g = ((const float4*)gamma)[t];
  u16x4 r;
  r.x = f2bf(v.x * inv * g.x);
  r.y = f2bf(v.y * inv * g.y);
  r.z = f2bf(v.z * inv * g.z);
  r.w = f2bf(v.w * inv * g.w);
  ((u16x4*)(o + (size_t)row * 1024))[t] = r;
}

// ========== 128x128 BK=64 single-buffer GEMM (4 blocks/CU) ==================
// 8x8-block super-tiles in the swizzle: L2 working set 2MB(A)+2MB(B) per XCD.
// EPI 0: bf16 = acc * (n0<ncut?scale:1)
// EPI 1: fp32 = acc + ep_fp32[idx]
// EPI 3: fp32 unsafeAtomicAdd(out+idx, acc) (split-K via blockIdx.z)
// EPI 4: fused SwiGLU epilogue (gate cols 0-63 | up 64-127 per ff-group)
template <int EPI>
__global__ __launch_bounds__(256, 4)
void gemm128(const u16* __restrict__ A, const u16* __restrict__ B,
             void* out, const void* ep, int M, int N, int KLOOP, int KS,
             float scale, int ncut) {
  __shared__ u16 smem[2][8192];
  u16* const sA = smem[0];
  u16* const sB = smem[1];

  const int tid = threadIdx.x;
  const int lane = tid & 63;
  const int w = tid >> 6;
  const int wr = w >> 1, wc = w & 1;
  const int lr = lane & 15, lk = lane >> 4;

  A += (size_t)blockIdx.z * KLOOP;
  B += (size_t)blockIdx.z * KLOOP;

  // bijective XCD swizzle + 8x8-block super-tiles (requires nx%8==0, nm%8==0)
  const int nx = gridDim.x;
  const int nwg = nx * gridDim.y;
  const int flat = blockIdx.y * nx + blockIdx.x;
  const int qq = nwg >> 3, rr = nwg & 7;
  const int xcd = flat & 7, off = flat >> 3;
  const int swz = (xcd < rr ? xcd * (qq + 1) : rr * (qq + 1) + (xcd - rr) * qq) + off;
  const int sr = nx * 8;
  const int g8 = swz / sr, rem = swz % sr;
  const int grp = rem >> 6, r6 = rem & 63;
  const int m0 = (g8 * 8 + (r6 & 7)) * 128;
  const int n0 = (grp * 8 + (r6 >> 3)) * 128;

  f32x4 acc[4][4];
  #pragma unroll
  for (int i = 0; i < 4; i++)
    #pragma unroll
    for (int j = 0; j < 4; j++) acc[i][j] = (f32x4){0.f, 0.f, 0.f, 0.f};

  for (int kt = 0; kt < KLOOP; kt += 64) {
    __syncthreads();
    #pragma unroll
    for (int r = 0; r < 4; r++) {
      const int q = r * 256 + tid;
      const int row = q >> 3;
      const int cs = (q & 7) ^ (row & 7);
      gload_lds16(A + (size_t)(m0 + row) * KS + kt + cs * 8, (char*)sA + q * 16);
      gload_lds16(B + (size_t)(n0 + row) * KS + kt + cs * 8, (char*)sB + q * 16);
    }
    __syncthreads();
    #pragma unroll
    for (int kk = 0; kk < 2; kk++) {
      bf16x8 a_[4], b_[4];
      #pragma unroll
      for (int i = 0; i < 4; i++)
        a_[i] = *(const bf16x8*)&sA[(wr * 64 + i * 16 + lr) * 64 +
                                    (((kk * 4 + lk) ^ (lr & 7)) * 8)];
      #pragma unroll
      for (int j = 0; j < 4; j++)
        b_[j] = *(const bf16x8*)&sB[(wc * 64 + j * 16 + lr) * 64 +
                                    (((kk * 4 + lk) ^ (lr & 7)) * 8)];
      #pragma unroll
      for (int i = 0; i < 4; i++)
        #pragma unroll
        for (int j = 0; j < 4; j++)
          acc[i][j] = __builtin_amdgcn_mfma_f32_16x16x32_bf16(a_[i], b_[j], acc[i][j], 0, 0, 0);
    }
  }

  if constexpr (EPI == 1 || EPI == 3) {
    #pragma unroll
    for (int i = 0; i < 4; i++)
      #pragma unroll
      for (int j = 0; j < 4; j++)
        #pragma unroll
        for (int r = 0; r < 4; r++) {
          const int grow = m0 + wr * 64 + i * 16 + lk * 4 + r;
          const int gcol = n0 + wc * 64 + j * 16 + lr;
          const size_t idx = (size_t)grow * N + gcol;
          if (EPI == 1) ((float*)out)[idx] = ((const float*)ep)[idx] + acc[i][j][r];
          else          unsafeAtomicAdd((float*)out + idx, acc[i][j][r]);
        }
  } else {
    u16* const smC = smem[0];
    const float s = (EPI == 0 && n0 < ncut) ? scale : 1.0f;
    __syncthreads();
    #pragma unroll
    for (int i = 0; i < 4; i++)
      #pragma unroll
      for (int j = 0; j < 4; j++)
        #pragma unroll
        for (int r = 0; r < 4; r++) {
          const int row = wr * 64 + i * 16 + lk * 4 + r;
          const int col = wc * 64 + j * 16 + lr;
          smC[row * 128 + (col ^ ((row & 7) << 3))] = f2bf(acc[i][j][r] * s);
        }
    __syncthreads();
    if constexpr (EPI == 4) {
      #pragma unroll
      for (int it = 0; it < 4; it++) {
        const int fl = it * 256 + tid;
        const int row = fl >> 3;
        const int ch = fl & 7;
        bf16x8 gvv = *(const bf16x8*)&smC[row * 128 + ((ch ^ (row & 7)) * 8)];
        bf16x8 uvv = *(const bf16x8*)&smC[row * 128 + (((ch + 8) ^ (row & 7)) * 8)];
        bf16x8 ov;
        #pragma unroll
        for (int k = 0; k < 8; k++) {
          float g = bf2f((u16)gvv[k]);
          float u = bf2f((u16)uvv[k]);
          float sg = g / (1.f + __expf(-g));
          ov[k] = (short)f2bf(sg * u);
        }
        *(bf16x8*)((u16*)out + (size_t)(m0 + row) * N + (n0 >> 1) + ch * 8) = ov;
      }
    } else {
      #pragma unroll
      for (int it = 0; it < 8; it++) {
        const int fl = it * 256 + tid;
        const int row = fl >> 4;
        const int ch = fl & 15;
        bf16x8 cv = *(const bf16x8*)&smC[row * 128 + ((ch ^ (row & 7)) * 8)];
        const size_t gidx = (size_t)(m0 + row) * N + n0 + ch * 8;
        *(bf16x8*)((u16*)out + gidx) = cv;
      }
    }
  }
}

// ---------------- V transpose from packed qkv: -> vt[bh=64][d=64][s=2048] ----
__global__ __launch_bounds__(256) void vtrans(const u16* __restrict__ qkv,
                                              u16* __restrict__ vt) {
  __shared__ u16 T[64][72];
  const int t = threadIdx.x;
  const int s0 = blockIdx.x * 64;
  const int h = blockIdx.y;
  const int b = blockIdx.z;
  const int sl = t >> 2, dl = (t & 3) * 16;
  const u16* src = qkv + ((size_t)(b * 2048 + s0 + sl)) * 3072 + 2048 + h * 64 + dl;
  bf16x8 v0 = *(const bf16x8*)src;
  bf16x8 v1 = *(const bf16x8*)(src + 8);
  #pragma unroll
  for (int j = 0; j < 8; j++) T[dl + j][sl] = (u16)v0[j];
  #pragma unroll
  for (int j = 0; j < 8; j++) T[dl + 8 + j][sl] = (u16)v1[j];
  __syncthreads();
  const int dl2 = t >> 2, sl2 = (t & 3) * 16;
  u16* dst = vt + ((size_t)((b * 16 + h) * 64 + dl2)) * 2048 + s0 + sl2;
  *(bf16x8*)dst = *(const bf16x8*)&T[dl2][sl2];
  *(bf16x8*)(dst + 8) = *(const bf16x8*)&T[dl2][sl2 + 8];
}

// ---------------- causal flash attention v5 ----------------
// 1024 blocks (one q-tile each), longest-first dispatch (qt=15 first),
// 4 blocks/CU for inter-block latency hiding. v3 softmax (exp2, defer-max,
// tree reductions, cvt_pk, setprio).
__global__ __launch_bounds__(256, 4)
void attn_fwd5(const u16* __restrict__ qkv, const u16* __restrict__ vt,
               u16* __restrict__ o) {
  __shared__ u16 sm[9216];
  u16* const smK = sm;
  u16* const smV = sm + 4096;

  const int tid = threadIdx.x;
  const int lane = tid & 63;
  const int w = tid >> 6;
  const int hi = lane >> 5;
  const int ln = lane & 31;

  const int flat = blockIdx.x;
  const int qt = 15 - (flat >> 6);     // longest jobs dispatched first
  const int bh = flat & 63;
  const int b = bh >> 4, h = bh & 15;

  const int qbase = qt * 128;
  const int qw0 = qbase + w * 32;
  const int qglob = qw0 + ln;
  const int nkb = qt * 2 + 2;

  bf16x8 qf[4];
  {
    const u16* qp = qkv + ((size_t)(b * 2048 + qw0 + ln)) * 3072 + h * 64 + hi * 8;
    #pragma unroll
    for (int c = 0; c < 4; c++) qf[c] = *(const bf16x8*)(qp + c * 16);
  }

  f32x16 accO[2];
  #pragma unroll
  for (int i = 0; i < 2; i++)
    #pragma unroll
    for (int r = 0; r < 16; r++) accO[i][r] = 0.f;
  float mrun = -1e30f, lsum = 0.f;

  for (int kb = 0; kb < nkb; kb++) {
    const int kbase = kb * 64;
    __syncthreads();
    #pragma unroll
    for (int r = 0; r < 2; r++) {
      const int cb = w * 128 + r * 64;
      const int ci = cb + lane;
      {
        const int key = ci >> 3, gch = (ci & 7) ^ (key & 7);
        const u16* src = qkv + ((size_t)(b * 2048 + kbase + key)) * 3072 + 1024 + h * 64 + gch * 8;
        gload_lds16(src, (char*)smK + cb * 16);
      }
      {
        const int d = ci >> 3, gch = (ci & 7) ^ (d & 7);
        const u16* src = vt + ((size_t)(bh * 64 + d)) * 2048 + kbase + gch * 8;
        gload_lds16(src, (char*)smV + cb * 16);
      }
    }
    __syncthreads();

    if (kbase <= qw0 + 31) {
      f32x16 st[2];
      #pragma unroll
      for (int kt = 0; kt < 2; kt++) {
        #pragma unroll
        for (int r = 0; r < 16; r++) st[kt][r] = 0.f;
      }
      __builtin_amdgcn_s_setprio(1);
      #pragma unroll
      for (int kt = 0; kt < 2; kt++)
        #pragma unroll
        for (int c = 0; c < 4; c++) {
          const int row = kt * 32 + ln;
          const int sch = (c * 2 + hi) ^ (ln & 7);
          bf16x8 kf = *(const bf16x8*)((const char*)smK + row * 128 + sch * 16);
          st[kt] = __builtin_amdgcn_mfma_f32_32x32x16_bf16(kf, qf[c], st[kt], 0, 0, 0);
        }
      __builtin_amdgcn_s_setprio(0);
      if (kbase + 63 > qw0) {
        #pragma unroll
        for (int kt = 0; kt < 2; kt++)
          #pragma unroll
          for (int r = 0; r < 16; r++) {
            const int kk = kbase + kt * 32 + (r & 3) + 8 * (r >> 2) + 4 * hi;
            if (kk > qglob) st[kt][r] = -1e30f;
          }
      }
      float t16[16];
      #pragma unroll
      for (int i = 0; i < 16; i++) t16[i] = fmaxf(st[0][i], st[1][i]);
      #pragma unroll
      for (int s = 8; s > 0; s >>= 1)
        #pragma unroll
        for (int i = 0; i < 8; i++)
          if (i < s) t16[i] = fmaxf(t16[i], t16[i + s]);
      float pm = t16[0];
      pm = fmaxf(pm, __shfl_xor(pm, 32));
      if (!__all(pm - mrun <= 8.f)) {
        const float mnew = fmaxf(mrun, pm);
        const float alpha = exp2a(mrun - mnew);
        lsum *= alpha;
        accO[0] *= alpha;
        accO[1] *= alpha;
        mrun = mnew;
      }
      #pragma unroll
      for (int kt = 0; kt < 2; kt++)
        #pragma unroll
        for (int r = 0; r < 16; r++) st[kt][r] = exp2a(st[kt][r] - mrun);
      float s16[16];
      #pragma unroll
      for (int i = 0; i < 16; i++) s16[i] = st[0][i] + st[1][i];
      #pragma unroll
      for (int s = 8; s > 0; s >>= 1)
        #pragma unroll
        for (int i = 0; i < 8; i++)
          if (i < s) s16[i] = s16[i] + s16[i + s];
      float ps = s16[0];
      ps += __shfl_xor(ps, 32);
      lsum += ps;

      #pragma unroll
      for (int kt = 0; kt < 2; kt++) {
        u32 pw[8], px[8];
        #pragma unroll
        for (int i = 0; i < 8; i++) pw[i] = cvtpk(st[kt][2 * i], st[kt][2 * i + 1]);
        #pragma unroll
        for (int i = 0; i < 8; i++) px[i] = (u32)__shfl_xor((int)pw[i], 32);
        union { u32 wd[4]; bf16x8 v; } f0, f1;
        f0.wd[0] = hi ? px[2] : pw[0];
        f0.wd[1] = hi ? px[3] : pw[1];
        f0.wd[2] = hi ? pw[2] : px[0];
        f0.wd[3] = hi ? pw[3] : px[1];
        f1.wd[0] = hi ? px[6] : pw[4];
        f1.wd[1] = hi ? px[7] : pw[5];
        f1.wd[2] = hi ? pw[6] : px[4];
        f1.wd[3] = hi ? pw[7] : px[5];
        __builtin_amdgcn_s_setprio(1);
        #pragma unroll
        for (int d0 = 0; d0 < 2; d0++) {
          #pragma unroll
          for (int kc = 0; kc < 2; kc++) {
            const int drow = d0 * 32 + ln;
            const int sch = (kt * 4 + kc * 2 + hi) ^ (ln & 7);
            bf16x8 vf = *(const bf16x8*)((const char*)smV + drow * 128 + sch * 16);
            accO[d0] = __builtin_amdgcn_mfma_f32_32x32x16_bf16(vf, kc ? f1.v : f0.v,
                                                               accO[d0], 0, 0, 0);
          }
        }
        __builtin_amdgcn_s_setprio(0);
      }
    }
  }

  __syncthreads();
  const float inv = 1.0f / lsum;
  #pragma unroll
  for (int d0 = 0; d0 < 2; d0++)
    #pragma unroll
    for (int r = 0; r < 16; r++) {
      const int d = d0 * 32 + (r & 3) + 8 * (r >> 2) + 4 * hi;
      sm[(w * 32 + ln) * 72 + d] = f2bf(accO[d0][r] * inv);
    }
  __syncthreads();
  const int ql = tid >> 1, dh = (tid & 1) * 32;
  const u16* srcp = &sm[ql * 72 + dh];
  u16* dst = o + ((size_t)(b * 2048 + qbase + ql)) * 1024 + h * 64 + dh;
  #pragma unroll
  for (int j = 0; j < 4; j++)
    *(bf16x8*)(dst + j * 8) = *(const bf16x8*)(srcp + j * 8);
}

// ---------------- host ----------------
extern "C" void kernel_launch(void* const* d_in, const int* in_sizes, int n_in,
                              void* d_out, int out_size, void* d_ws, size_t ws_size,
                              hipStream_t stream) {
  const float* x      = (const float*)d_in[0];
  const float* W_q    = (const float*)d_in[1];
  const float* W_k    = (const float*)d_in[2];
  const float* W_v    = (const float*)d_in[3];
  const float* W_o    = (const float*)d_in[4];
  const float* gamma1 = (const float*)d_in[5];
  const float* gamma2 = (const float*)d_in[6];
  const float* W1     = (const float*)d_in[7];
  const float* W2     = (const float*)d_in[8];
  const float* W3     = (const float*)d_in[9];

  char* ws = (char*)d_ws;
  const size_t MB = 1ull << 20;
  u16* qkvw  = (u16*)(ws + 0 * MB);
  u16* Wo_b  = (u16*)(ws + 6 * MB);
  u16* W13   = (u16*)(ws + 8 * MB);
  u16* W2_b  = (u16*)(ws + 24 * MB);
  u16* xn    = (u16*)(ws + 32 * MB);
  u16* qkvb  = (u16*)(ws + 48 * MB);
  u16* attnb = (u16*)(ws + 96 * MB);
  u16* vtb   = (u16*)(ws + 112 * MB);
  u16* hbuf  = (u16*)(ws + 128 * MB);
  float* x1  = (float*)d_out;

  castw<<<1024, 256, 0, stream>>>(W_q, qkvw, 262144);
  castw<<<1024, 256, 0, stream>>>(W_k, qkvw + 1024 * 1024, 262144);
  castw<<<1024, 256, 0, stream>>>(W_v, qkvw + 2048 * 1024, 262144);
  castw<<<1024, 256, 0, stream>>>(W_o, Wo_b, 262144);
  castw_pack<<<4096, 256, 0, stream>>>(W1, W13, 0);
  castw_pack<<<4096, 256, 0, stream>>>(W3, W13, 1);
  castw<<<4096, 256, 0, stream>>>(W2, W2_b, 1048576);

  rmsnorm_k<<<8192, 256, 0, stream>>>(x, gamma1, xn);
  gemm128<0><<<dim3(24, 64), 256, 0, stream>>>(xn, qkvw, qkvb, nullptr,
                                               8192, 3072, 1024, 1024,
                                               0.125f * 1.44269504f, 1024);
  vtrans<<<dim3(32, 16, 4), 256, 0, stream>>>(qkvb, vtb);
  attn_fwd5<<<dim3(1024), 256, 0, stream>>>(qkvb, vtb, attnb);
  gemm128<1><<<dim3(8, 64), 256, 0, stream>>>(attnb, Wo_b, x1, x,
                                              8192, 1024, 1024, 1024, 1.0f, 0);

  rmsnorm_k<<<8192, 256, 0, stream>>>(x1, gamma2, xn);
  gemm128<4><<<dim3(64, 64), 256, 0, stream>>>(xn, W13, hbuf, nullptr,
                                               8192, 4096, 1024, 1024, 1.0f, 0);
  gemm128<3><<<dim3(8, 64, 2), 256, 0, stream>>>(hbuf, W2_b, (float*)d_out, nullptr,
                                                 8192, 1024, 2048, 4096, 1.0f, 0);
}

// Round 13
// 448.382 us; speedup vs baseline: 1.1380x; 1.0433x over previous
//
#include <hip/hip_runtime.h>
#include <cstdint>
#include <cstddef>

typedef unsigned short u16;
typedef unsigned int u32;
typedef short bf16x8 __attribute__((ext_vector_type(8)));
typedef float f32x4 __attribute__((ext_vector_type(4)));
typedef float f32x16 __attribute__((ext_vector_type(16)));
typedef u16 u16x4 __attribute__((ext_vector_type(4)));

__device__ __forceinline__ u16 f2bf(float f) {
  u32 u = __float_as_uint(f);
  return (u16)((u + 0x7FFFu + ((u >> 16) & 1u)) >> 16);
}
__device__ __forceinline__ float bf2f(u16 h) {
  return __uint_as_float(((u32)h) << 16);
}
__device__ __forceinline__ u32 cvtpk(float lo, float hi) {
  u32 r;
  asm("v_cvt_pk_bf16_f32 %0, %1, %2" : "=v"(r) : "v"(lo), "v"(hi));
  return r;
}
__device__ __forceinline__ float exp2a(float x) {
  float r;
  asm("v_exp_f32 %0, %1" : "=v"(r) : "v"(x));
  return r;
}

__device__ __forceinline__ void gload_lds16(const void* g, void* l) {
  __builtin_amdgcn_global_load_lds((const __attribute__((address_space(1))) u32*)g,
                                   (__attribute__((address_space(3))) u32*)l, 16, 0, 0);
}

// ------- merged weight casts: Wq|Wk|Wv -> qkvw, Wo -> Wo_b, W2 -> W2_b -----
__global__ __launch_bounds__(256) void castw_multi(
    const float* __restrict__ Wq, const float* __restrict__ Wk,
    const float* __restrict__ Wv, const float* __restrict__ Wo,
    const float* __restrict__ W2, u16* __restrict__ qkvw,
    u16* __restrict__ Wo_b, u16* __restrict__ W2_b) {
  const int bid = blockIdx.x;
  const float* src;
  u16x4* dst;
  int i;
  if (bid < 3072) {
    src = (bid < 1024) ? Wq : (bid < 2048) ? Wk : Wv;
    dst = (u16x4*)qkvw + (bid >> 10) * 262144;
    i = (bid & 1023) * 256 + threadIdx.x;
  } else if (bid < 4096) {
    src = Wo;
    dst = (u16x4*)Wo_b;
    i = (bid - 3072) * 256 + threadIdx.x;
  } else {
    src = W2;
    dst = (u16x4*)W2_b;
    i = (bid - 4096) * 256 + threadIdx.x;
  }
  float4 v = ((const float4*)src)[i];
  u16x4 r;
  r.x = f2bf(v.x); r.y = f2bf(v.y); r.z = f2bf(v.z); r.w = f2bf(v.w);
  dst[i] = r;
}

// cast + interleave pack: W1/W3 [4096][1024] -> W13 [8192][1024]
// blockIdx.y = half (0 = W1/gate, 1 = W3/up)
__global__ __launch_bounds__(256) void castw_pack2(const float* __restrict__ W1,
                                                   const float* __restrict__ W3,
                                                   u16* __restrict__ dst) {
  const int half = blockIdx.y;
  const float* src = half ? W3 : W1;
  int i = blockIdx.x * 256 + threadIdx.x;
  float4 v = ((const float4*)src)[i];
  const int n = i >> 8;
  const int c4 = i & 255;
  const int orow = ((n >> 6) << 7) + (half << 6) + (n & 63);
  u16x4 r;
  r.x = f2bf(v.x); r.y = f2bf(v.y); r.z = f2bf(v.z); r.w = f2bf(v.w);
  ((u16x4*)dst)[orow * 256 + c4] = r;
}

// ---------------- RMSNorm: fp32 [rows,1024] -> bf16 ----------------
__global__ __launch_bounds__(256) void rmsnorm_k(const float* __restrict__ x,
                                                 const float* __restrict__ gamma,
                                                 u16* __restrict__ o) {
  const int row = blockIdx.x;
  const int t = threadIdx.x;
  float4 v = ((const float4*)(x + (size_t)row * 1024))[t];
  float ss = v.x * v.x + v.y * v.y + v.z * v.z + v.w * v.w;
  #pragma unroll
  for (int m = 1; m < 64; m <<= 1) ss += __shfl_xor(ss, m);
  __shared__ float wsum[4];
  if ((t & 63) == 0) wsum[t >> 6] = ss;
  __syncthreads();
  float tot = wsum[0] + wsum[1] + wsum[2] + wsum[3];
  float inv = rsqrtf(tot * (1.0f / 1024.0f) + 1e-5f);
  float4 g = ((const float4*)gamma)[t];
  u16x4 r;
  r.x = f2bf(v.x * inv * g.x);
  r.y = f2bf(v.y * inv * g.y);
  r.z = f2bf(v.z * inv * g.z);
  r.w = f2bf(v.w * inv * g.w);
  ((u16x4*)(o + (size_t)row * 1024))[t] = r;
}

// ========== 128x128 BK=64 single-buffer GEMM (4 blocks/CU) ==================
// EPI 0: bf16 = acc * (n0<ncut?scale:1)
// EPI 1: fp32 = acc + ep_fp32[idx]
// EPI 3: fp32 unsafeAtomicAdd(out+idx, acc) (split-K via blockIdx.z)
// EPI 4: fused SwiGLU epilogue (gate cols 0-63 | up 64-127 per ff-group)
// EPI 5: QKV variant: n0<2048 -> EPI0 path into out(qkvb);
//        n0>=2048 (V) -> transposed write into ep as vt[bh][64][2048]
template <int EPI>
__global__ __launch_bounds__(256, 4)
void gemm128(const u16* __restrict__ A, const u16* __restrict__ B,
             void* out, const void* ep, int M, int N, int KLOOP, int KS,
             float scale, int ncut) {
  __shared__ u16 smem[2][8192];
  u16* const sA = smem[0];
  u16* const sB = smem[1];

  const int tid = threadIdx.x;
  const int lane = tid & 63;
  const int w = tid >> 6;
  const int wr = w >> 1, wc = w & 1;
  const int lr = lane & 15, lk = lane >> 4;

  A += (size_t)blockIdx.z * KLOOP;
  B += (size_t)blockIdx.z * KLOOP;

  // bijective XCD swizzle + 8x8-block super-tiles (requires nx%8==0, nm%8==0)
  const int nx = gridDim.x;
  const int nwg = nx * gridDim.y;
  const int flat = blockIdx.y * nx + blockIdx.x;
  const int qq = nwg >> 3, rr = nwg & 7;
  const int xcd = flat & 7, off = flat >> 3;
  const int swz = (xcd < rr ? xcd * (qq + 1) : rr * (qq + 1) + (xcd - rr) * qq) + off;
  const int sr = nx * 8;
  const int g8 = swz / sr, rem = swz % sr;
  const int grp = rem >> 6, r6 = rem & 63;
  const int m0 = (g8 * 8 + (r6 & 7)) * 128;
  const int n0 = (grp * 8 + (r6 >> 3)) * 128;

  f32x4 acc[4][4];
  #pragma unroll
  for (int i = 0; i < 4; i++)
    #pragma unroll
    for (int j = 0; j < 4; j++) acc[i][j] = (f32x4){0.f, 0.f, 0.f, 0.f};

  for (int kt = 0; kt < KLOOP; kt += 64) {
    __syncthreads();
    #pragma unroll
    for (int r = 0; r < 4; r++) {
      const int q = r * 256 + tid;
      const int row = q >> 3;
      const int cs = (q & 7) ^ (row & 7);
      gload_lds16(A + (size_t)(m0 + row) * KS + kt + cs * 8, (char*)sA + q * 16);
      gload_lds16(B + (size_t)(n0 + row) * KS + kt + cs * 8, (char*)sB + q * 16);
    }
    __syncthreads();
    #pragma unroll
    for (int kk = 0; kk < 2; kk++) {
      bf16x8 a_[4], b_[4];
      #pragma unroll
      for (int i = 0; i < 4; i++)
        a_[i] = *(const bf16x8*)&sA[(wr * 64 + i * 16 + lr) * 64 +
                                    (((kk * 4 + lk) ^ (lr & 7)) * 8)];
      #pragma unroll
      for (int j = 0; j < 4; j++)
        b_[j] = *(const bf16x8*)&sB[(wc * 64 + j * 16 + lr) * 64 +
                                    (((kk * 4 + lk) ^ (lr & 7)) * 8)];
      #pragma unroll
      for (int i = 0; i < 4; i++)
        #pragma unroll
        for (int j = 0; j < 4; j++)
          acc[i][j] = __builtin_amdgcn_mfma_f32_16x16x32_bf16(a_[i], b_[j], acc[i][j], 0, 0, 0);
    }
  }

  if constexpr (EPI == 1 || EPI == 3) {
    #pragma unroll
    for (int i = 0; i < 4; i++)
      #pragma unroll
      for (int j = 0; j < 4; j++)
        #pragma unroll
        for (int r = 0; r < 4; r++) {
          const int grow = m0 + wr * 64 + i * 16 + lk * 4 + r;
          const int gcol = n0 + wc * 64 + j * 16 + lr;
          const size_t idx = (size_t)grow * N + gcol;
          if (EPI == 1) ((float*)out)[idx] = ((const float*)ep)[idx] + acc[i][j][r];
          else          unsafeAtomicAdd((float*)out + idx, acc[i][j][r]);
        }
  } else {
    bool vpath = false;
    if constexpr (EPI == 5) vpath = (n0 >= 2048);
    if (vpath) {
      // transposed-V: bounce acc into LDS transposed, write vt[bh][d][s]
      u16* const smT = smem[0];
      __syncthreads();
      #pragma unroll
      for (int i = 0; i < 4; i++)
        #pragma unroll
        for (int j = 0; j < 4; j++)
          #pragma unroll
          for (int r = 0; r < 4; r++) {
            const int row = wr * 64 + i * 16 + lk * 4 + r;   // s-local
            const int col = wc * 64 + j * 16 + lr;           // d-local
            smT[col * 128 + (row ^ ((col & 7) << 3))] = f2bf(acc[i][j][r]);
          }
      __syncthreads();
      u16* const vt = (u16*)const_cast<void*>(ep);
      const int b = m0 >> 11;
      const int sbase = m0 & 2047;
      #pragma unroll
      for (int it = 0; it < 8; it++) {
        const int fl = it * 256 + tid;
        const int trow = fl >> 4;          // d-local 0..127
        const int tch = fl & 15;           // s-chunk
        bf16x8 cv = *(const bf16x8*)&smT[trow * 128 + ((tch * 8) ^ ((trow & 7) << 3))];
        const int dg = n0 - 2048 + trow;
        const int h = dg >> 6, d = dg & 63;
        *(bf16x8*)(vt + (((size_t)(b * 16 + h) * 64 + d) * 2048 + sbase + tch * 8)) = cv;
      }
    } else {
      u16* const smC = smem[0];
      const float s = ((EPI == 0 || EPI == 5) && n0 < ncut) ? scale : 1.0f;
      __syncthreads();
      #pragma unroll
      for (int i = 0; i < 4; i++)
        #pragma unroll
        for (int j = 0; j < 4; j++)
          #pragma unroll
          for (int r = 0; r < 4; r++) {
            const int row = wr * 64 + i * 16 + lk * 4 + r;
            const int col = wc * 64 + j * 16 + lr;
            smC[row * 128 + (col ^ ((row & 7) << 3))] = f2bf(acc[i][j][r] * s);
          }
      __syncthreads();
      if constexpr (EPI == 4) {
        #pragma unroll
        for (int it = 0; it < 4; it++) {
          const int fl = it * 256 + tid;
          const int row = fl >> 3;
          const int ch = fl & 7;
          bf16x8 gvv = *(const bf16x8*)&smC[row * 128 + ((ch ^ (row & 7)) * 8)];
          bf16x8 uvv = *(const bf16x8*)&smC[row * 128 + (((ch + 8) ^ (row & 7)) * 8)];
          bf16x8 ov;
          #pragma unroll
          for (int k = 0; k < 8; k++) {
            float g = bf2f((u16)gvv[k]);
            float u = bf2f((u16)uvv[k]);
            float sg = g / (1.f + __expf(-g));
            ov[k] = (short)f2bf(sg * u);
          }
          *(bf16x8*)((u16*)out + (size_t)(m0 + row) * N + (n0 >> 1) + ch * 8) = ov;
        }
      } else {
        #pragma unroll
        for (int it = 0; it < 8; it++) {
          const int fl = it * 256 + tid;
          const int row = fl >> 4;
          const int ch = fl & 15;
          bf16x8 cv = *(const bf16x8*)&smC[row * 128 + ((ch ^ (row & 7)) * 8)];
          const size_t gidx = (size_t)(m0 + row) * N + n0 + ch * 8;
          *(bf16x8*)((u16*)out + gidx) = cv;
        }
      }
    }
  }
}

// ---------------- causal flash attention v5 ----------------
__global__ __launch_bounds__(256, 4)
void attn_fwd5(const u16* __restrict__ qkv, const u16* __restrict__ vt,
               u16* __restrict__ o) {
  __shared__ u16 sm[9216];
  u16* const smK = sm;
  u16* const smV = sm + 4096;

  const int tid = threadIdx.x;
  const int lane = tid & 63;
  const int w = tid >> 6;
  const int hi = lane >> 5;
  const int ln = lane & 31;

  const int flat = blockIdx.x;
  const int qt = 15 - (flat >> 6);
  const int bh = flat & 63;
  const int b = bh >> 4, h = bh & 15;

  const int qbase = qt * 128;
  const int qw0 = qbase + w * 32;
  const int qglob = qw0 + ln;
  const int nkb = qt * 2 + 2;

  bf16x8 qf[4];
  {
    const u16* qp = qkv + ((size_t)(b * 2048 + qw0 + ln)) * 3072 + h * 64 + hi * 8;
    #pragma unroll
    for (int c = 0; c < 4; c++) qf[c] = *(const bf16x8*)(qp + c * 16);
  }

  f32x16 accO[2];
  #pragma unroll
  for (int i = 0; i < 2; i++)
    #pragma unroll
    for (int r = 0; r < 16; r++) accO[i][r] = 0.f;
  float mrun = -1e30f, lsum = 0.f;

  for (int kb = 0; kb < nkb; kb++) {
    const int kbase = kb * 64;
    __syncthreads();
    #pragma unroll
    for (int r = 0; r < 2; r++) {
      const int cb = w * 128 + r * 64;
      const int ci = cb + lane;
      {
        const int key = ci >> 3, gch = (ci & 7) ^ (key & 7);
        const u16* src = qkv + ((size_t)(b * 2048 + kbase + key)) * 3072 + 1024 + h * 64 + gch * 8;
        gload_lds16(src, (char*)smK + cb * 16);
      }
      {
        const int d = ci >> 3, gch = (ci & 7) ^ (d & 7);
        const u16* src = vt + ((size_t)(bh * 64 + d)) * 2048 + kbase + gch * 8;
        gload_lds16(src, (char*)smV + cb * 16);
      }
    }
    __syncthreads();

    if (kbase <= qw0 + 31) {
      f32x16 st[2];
      #pragma unroll
      for (int kt = 0; kt < 2; kt++) {
        #pragma unroll
        for (int r = 0; r < 16; r++) st[kt][r] = 0.f;
      }
      __builtin_amdgcn_s_setprio(1);
      #pragma unroll
      for (int kt = 0; kt < 2; kt++)
        #pragma unroll
        for (int c = 0; c < 4; c++) {
          const int row = kt * 32 + ln;
          const int sch = (c * 2 + hi) ^ (ln & 7);
          bf16x8 kf = *(const bf16x8*)((const char*)smK + row * 128 + sch * 16);
          st[kt] = __builtin_amdgcn_mfma_f32_32x32x16_bf16(kf, qf[c], st[kt], 0, 0, 0);
        }
      __builtin_amdgcn_s_setprio(0);
      if (kbase + 63 > qw0) {
        #pragma unroll
        for (int kt = 0; kt < 2; kt++)
          #pragma unroll
          for (int r = 0; r < 16; r++) {
            const int kk = kbase + kt * 32 + (r & 3) + 8 * (r >> 2) + 4 * hi;
            if (kk > qglob) st[kt][r] = -1e30f;
          }
      }
      float t16[16];
      #pragma unroll
      for (int i = 0; i < 16; i++) t16[i] = fmaxf(st[0][i], st[1][i]);
      #pragma unroll
      for (int s = 8; s > 0; s >>= 1)
        #pragma unroll
        for (int i = 0; i < 8; i++)
          if (i < s) t16[i] = fmaxf(t16[i], t16[i + s]);
      float pm = t16[0];
      pm = fmaxf(pm, __shfl_xor(pm, 32));
      if (!__all(pm - mrun <= 8.f)) {
        const float mnew = fmaxf(mrun, pm);
        const float alpha = exp2a(mrun - mnew);
        lsum *= alpha;
        accO[0] *= alpha;
        accO[1] *= alpha;
        mrun = mnew;
      }
      #pragma unroll
      for (int kt = 0; kt < 2; kt++)
        #pragma unroll
        for (int r = 0; r < 16; r++) st[kt][r] = exp2a(st[kt][r] - mrun);
      float s16[16];
      #pragma unroll
      for (int i = 0; i < 16; i++) s16[i] = st[0][i] + st[1][i];
      #pragma unroll
      for (int s = 8; s > 0; s >>= 1)
        #pragma unroll
        for (int i = 0; i < 8; i++)
          if (i < s) s16[i] = s16[i] + s16[i + s];
      float ps = s16[0];
      ps += __shfl_xor(ps, 32);
      lsum += ps;

      #pragma unroll
      for (int kt = 0; kt < 2; kt++) {
        u32 pw[8], px[8];
        #pragma unroll
        for (int i = 0; i < 8; i++) pw[i] = cvtpk(st[kt][2 * i], st[kt][2 * i + 1]);
        #pragma unroll
        for (int i = 0; i < 8; i++) px[i] = (u32)__shfl_xor((int)pw[i], 32);
        union { u32 wd[4]; bf16x8 v; } f0, f1;
        f0.wd[0] = hi ? px[2] : pw[0];
        f0.wd[1] = hi ? px[3] : pw[1];
        f0.wd[2] = hi ? pw[2] : px[0];
        f0.wd[3] = hi ? pw[3] : px[1];
        f1.wd[0] = hi ? px[6] : pw[4];
        f1.wd[1] = hi ? px[7] : pw[5];
        f1.wd[2] = hi ? pw[6] : px[4];
        f1.wd[3] = hi ? pw[7] : px[5];
        __builtin_amdgcn_s_setprio(1);
        #pragma unroll
        for (int d0 = 0; d0 < 2; d0++) {
          #pragma unroll
          for (int kc = 0; kc < 2; kc++) {
            const int drow = d0 * 32 + ln;
            const int sch = (kt * 4 + kc * 2 + hi) ^ (ln & 7);
            bf16x8 vf = *(const bf16x8*)((const char*)smV + drow * 128 + sch * 16);
            accO[d0] = __builtin_amdgcn_mfma_f32_32x32x16_bf16(vf, kc ? f1.v : f0.v,
                                                               accO[d0], 0, 0, 0);
          }
        }
        __builtin_amdgcn_s_setprio(0);
      }
    }
  }

  __syncthreads();
  const float inv = 1.0f / lsum;
  #pragma unroll
  for (int d0 = 0; d0 < 2; d0++)
    #pragma unroll
    for (int r = 0; r < 16; r++) {
      const int d = d0 * 32 + (r & 3) + 8 * (r >> 2) + 4 * hi;
      sm[(w * 32 + ln) * 72 + d] = f2bf(accO[d0][r] * inv);
    }
  __syncthreads();
  const int ql = tid >> 1, dh = (tid & 1) * 32;
  const u16* srcp = &sm[ql * 72 + dh];
  u16* dst = o + ((size_t)(b * 2048 + qbase + ql)) * 1024 + h * 64 + dh;
  #pragma unroll
  for (int j = 0; j < 4; j++)
    *(bf16x8*)(dst + j * 8) = *(const bf16x8*)(srcp + j * 8);
}

// ---------------- host ----------------
extern "C" void kernel_launch(void* const* d_in, const int* in_sizes, int n_in,
                              void* d_out, int out_size, void* d_ws, size_t ws_size,
                              hipStream_t stream) {
  const float* x      = (const float*)d_in[0];
  const float* W_q    = (const float*)d_in[1];
  const float* W_k    = (const float*)d_in[2];
  const float* W_v    = (const float*)d_in[3];
  const float* W_o    = (const float*)d_in[4];
  const float* gamma1 = (const float*)d_in[5];
  const float* gamma2 = (const float*)d_in[6];
  const float* W1     = (const float*)d_in[7];
  const float* W2     = (const float*)d_in[8];
  const float* W3     = (const float*)d_in[9];

  char* ws = (char*)d_ws;
  const size_t MB = 1ull << 20;
  u16* qkvw  = (u16*)(ws + 0 * MB);
  u16* Wo_b  = (u16*)(ws + 6 * MB);
  u16* W13   = (u16*)(ws + 8 * MB);
  u16* W2_b  = (u16*)(ws + 24 * MB);
  u16* xn    = (u16*)(ws + 32 * MB);
  u16* qkvb  = (u16*)(ws + 48 * MB);
  u16* attnb = (u16*)(ws + 96 * MB);
  u16* vtb   = (u16*)(ws + 112 * MB);
  u16* hbuf  = (u16*)(ws + 128 * MB);
  float* x1  = (float*)d_out;

  castw_multi<<<8192, 256, 0, stream>>>(W_q, W_k, W_v, W_o, W2, qkvw, Wo_b, W2_b);
  castw_pack2<<<dim3(4096, 2), 256, 0, stream>>>(W1, W3, W13);

  rmsnorm_k<<<8192, 256, 0, stream>>>(x, gamma1, xn);
  // QKV (EPI5): Q/K -> qkvb (q pre-scaled into exp2 domain); V -> vtb transposed
  gemm128<5><<<dim3(24, 64), 256, 0, stream>>>(xn, qkvw, qkvb, vtb,
                                               8192, 3072, 1024, 1024,
                                               0.125f * 1.44269504f, 1024);
  attn_fwd5<<<dim3(1024), 256, 0, stream>>>(qkvb, vtb, attnb);
  gemm128<1><<<dim3(8, 64), 256, 0, stream>>>(attnb, Wo_b, x1, x,
                                              8192, 1024, 1024, 1024, 1.0f, 0);

  rmsnorm_k<<<8192, 256, 0, stream>>>(x1, gamma2, xn);
  gemm128<4><<<dim3(64, 64), 256, 0, stream>>>(xn, W13, hbuf, nullptr,
                                               8192, 4096, 1024, 1024, 1.0f, 0);
  gemm128<3><<<dim3(8, 64, 2), 256, 0, stream>>>(hbuf, W2_b, (float*)d_out, nullptr,
                                                 8192, 1024, 2048, 4096, 1.0f, 0);
}

// Round 14
// 440.175 us; speedup vs baseline: 1.1592x; 1.0186x over previous
//
#include <hip/hip_runtime.h>
#include <cstdint>
#include <cstddef>

typedef unsigned short u16;
typedef unsigned int u32;
typedef short bf16x8 __attribute__((ext_vector_type(8)));
typedef float f32x4 __attribute__((ext_vector_type(4)));
typedef float f32x16 __attribute__((ext_vector_type(16)));
typedef u16 u16x4 __attribute__((ext_vector_type(4)));

__device__ __forceinline__ u16 f2bf(float f) {
  u32 u = __float_as_uint(f);
  return (u16)((u + 0x7FFFu + ((u >> 16) & 1u)) >> 16);
}
__device__ __forceinline__ float bf2f(u16 h) {
  return __uint_as_float(((u32)h) << 16);
}
__device__ __forceinline__ u32 cvtpk(float lo, float hi) {
  u32 r;
  asm("v_cvt_pk_bf16_f32 %0, %1, %2" : "=v"(r) : "v"(lo), "v"(hi));
  return r;
}
__device__ __forceinline__ float exp2a(float x) {
  float r;
  asm("v_exp_f32 %0, %1" : "=v"(r) : "v"(x));
  return r;
}

__device__ __forceinline__ void gload_lds16(const void* g, void* l) {
  __builtin_amdgcn_global_load_lds((const __attribute__((address_space(1))) u32*)g,
                                   (__attribute__((address_space(3))) u32*)l, 16, 0, 0);
}

// ======= merged prep: weight casts + W13 pack + rmsnorm1 (one launch) ======
// bid [0,8192): castw_multi | [8192,16384): pack W1/W3 | [16384,24576): rmsnorm1
__global__ __launch_bounds__(256) void prep_all(
    const float* __restrict__ Wq, const float* __restrict__ Wk,
    const float* __restrict__ Wv, const float* __restrict__ Wo,
    const float* __restrict__ W2, const float* __restrict__ W1,
    const float* __restrict__ W3, const float* __restrict__ x,
    const float* __restrict__ gamma1, u16* __restrict__ qkvw,
    u16* __restrict__ Wo_b, u16* __restrict__ W2_b, u16* __restrict__ W13,
    u16* __restrict__ xn) {
  const int bid = blockIdx.x;
  const int t = threadIdx.x;
  if (bid < 8192) {
    const float* src;
    u16x4* dst;
    int i;
    if (bid < 3072) {
      src = (bid < 1024) ? Wq : (bid < 2048) ? Wk : Wv;
      dst = (u16x4*)qkvw + (bid >> 10) * 262144;
      i = (bid & 1023) * 256 + t;
    } else if (bid < 4096) {
      src = Wo;
      dst = (u16x4*)Wo_b;
      i = (bid - 3072) * 256 + t;
    } else {
      src = W2;
      dst = (u16x4*)W2_b;
      i = (bid - 4096) * 256 + t;
    }
    float4 v = ((const float4*)src)[i];
    u16x4 r;
    r.x = f2bf(v.x); r.y = f2bf(v.y); r.z = f2bf(v.z); r.w = f2bf(v.w);
    dst[i] = r;
  } else if (bid < 16384) {
    const int b2 = bid - 8192;
    const int half = b2 >> 12;
    const float* src = half ? W3 : W1;
    int i = (b2 & 4095) * 256 + t;
    float4 v = ((const float4*)src)[i];
    const int n = i >> 8;
    const int c4 = i & 255;
    const int orow = ((n >> 6) << 7) + (half << 6) + (n & 63);
    u16x4 r;
    r.x = f2bf(v.x); r.y = f2bf(v.y); r.z = f2bf(v.z); r.w = f2bf(v.w);
    ((u16x4*)W13)[orow * 256 + c4] = r;
  } else {
    const int row = bid - 16384;
    float4 v = ((const float4*)(x + (size_t)row * 1024))[t];
    float ss = v.x * v.x + v.y * v.y + v.z * v.z + v.w * v.w;
    #pragma unroll
    for (int m = 1; m < 64; m <<= 1) ss += __shfl_xor(ss, m);
    __shared__ float wsum[4];
    if ((t & 63) == 0) wsum[t >> 6] = ss;
    __syncthreads();
    float tot = wsum[0] + wsum[1] + wsum[2] + wsum[3];
    float inv = rsqrtf(tot * (1.0f / 1024.0f) + 1e-5f);
    float4 g = ((const float4*)gamma1)[t];
    u16x4 r;
    r.x = f2bf(v.x * inv * g.x);
    r.y = f2bf(v.y * inv * g.y);
    r.z = f2bf(v.z * inv * g.z);
    r.w = f2bf(v.w * inv * g.w);
    ((u16x4*)(xn + (size_t)row * 1024))[t] = r;
  }
}

// ---------------- RMSNorm: fp32 [rows,1024] -> bf16 ----------------
__global__ __launch_bounds__(256) void rmsnorm_k(const float* __restrict__ x,
                                                 const float* __restrict__ gamma,
                                                 u16* __restrict__ o) {
  const int row = blockIdx.x;
  const int t = threadIdx.x;
  float4 v = ((const float4*)(x + (size_t)row * 1024))[t];
  float ss = v.x * v.x + v.y * v.y + v.z * v.z + v.w * v.w;
  #pragma unroll
  for (int m = 1; m < 64; m <<= 1) ss += __shfl_xor(ss, m);
  __shared__ float wsum[4];
  if ((t & 63) == 0) wsum[t >> 6] = ss;
  __syncthreads();
  float tot = wsum[0] + wsum[1] + wsum[2] + wsum[3];
  float inv = rsqrtf(tot * (1.0f / 1024.0f) + 1e-5f);
  float4 g = ((const float4*)gamma)[t];
  u16x4 r;
  r.x = f2bf(v.x * inv * g.x);
  r.y = f2bf(v.y * inv * g.y);
  r.z = f2bf(v.z * inv * g.z);
  r.w = f2bf(v.w * inv * g.w);
  ((u16x4*)(o + (size_t)row * 1024))[t] = r;
}

// ========== 128x128 BK=64 single-buffer GEMM (4 blocks/CU) ==================
// EPI 0: bf16 = acc * (n0<ncut?scale:1)
// EPI 4: fused SwiGLU epilogue
// EPI 5: QKV variant (V transposed into ep as vt)
template <int EPI>
__global__ __launch_bounds__(256, 4)
void gemm128(const u16* __restrict__ A, const u16* __restrict__ B,
             void* out, const void* ep, int M, int N, int KLOOP, int KS,
             float scale, int ncut) {
  __shared__ u16 smem[2][8192];
  u16* const sA = smem[0];
  u16* const sB = smem[1];

  const int tid = threadIdx.x;
  const int lane = tid & 63;
  const int w = tid >> 6;
  const int wr = w >> 1, wc = w & 1;
  const int lr = lane & 15, lk = lane >> 4;

  const int nx = gridDim.x;
  const int nwg = nx * gridDim.y;
  const int flat = blockIdx.y * nx + blockIdx.x;
  const int qq = nwg >> 3, rr = nwg & 7;
  const int xcd = flat & 7, off = flat >> 3;
  const int swz = (xcd < rr ? xcd * (qq + 1) : rr * (qq + 1) + (xcd - rr) * qq) + off;
  const int sr = nx * 8;
  const int g8 = swz / sr, rem = swz % sr;
  const int grp = rem >> 6, r6 = rem & 63;
  const int m0 = (g8 * 8 + (r6 & 7)) * 128;
  const int n0 = (grp * 8 + (r6 >> 3)) * 128;

  f32x4 acc[4][4];
  #pragma unroll
  for (int i = 0; i < 4; i++)
    #pragma unroll
    for (int j = 0; j < 4; j++) acc[i][j] = (f32x4){0.f, 0.f, 0.f, 0.f};

  for (int kt = 0; kt < KLOOP; kt += 64) {
    __syncthreads();
    #pragma unroll
    for (int r = 0; r < 4; r++) {
      const int q = r * 256 + tid;
      const int row = q >> 3;
      const int cs = (q & 7) ^ (row & 7);
      gload_lds16(A + (size_t)(m0 + row) * KS + kt + cs * 8, (char*)sA + q * 16);
      gload_lds16(B + (size_t)(n0 + row) * KS + kt + cs * 8, (char*)sB + q * 16);
    }
    __syncthreads();
    #pragma unroll
    for (int kk = 0; kk < 2; kk++) {
      bf16x8 a_[4], b_[4];
      #pragma unroll
      for (int i = 0; i < 4; i++)
        a_[i] = *(const bf16x8*)&sA[(wr * 64 + i * 16 + lr) * 64 +
                                    (((kk * 4 + lk) ^ (lr & 7)) * 8)];
      #pragma unroll
      for (int j = 0; j < 4; j++)
        b_[j] = *(const bf16x8*)&sB[(wc * 64 + j * 16 + lr) * 64 +
                                    (((kk * 4 + lk) ^ (lr & 7)) * 8)];
      #pragma unroll
      for (int i = 0; i < 4; i++)
        #pragma unroll
        for (int j = 0; j < 4; j++)
          acc[i][j] = __builtin_amdgcn_mfma_f32_16x16x32_bf16(a_[i], b_[j], acc[i][j], 0, 0, 0);
    }
  }

  bool vpath = false;
  if constexpr (EPI == 5) vpath = (n0 >= 2048);
  if (vpath) {
    u16* const smT = smem[0];
    __syncthreads();
    #pragma unroll
    for (int i = 0; i < 4; i++)
      #pragma unroll
      for (int j = 0; j < 4; j++)
        #pragma unroll
        for (int r = 0; r < 4; r++) {
          const int row = wr * 64 + i * 16 + lk * 4 + r;
          const int col = wc * 64 + j * 16 + lr;
          smT[col * 128 + (row ^ ((col & 7) << 3))] = f2bf(acc[i][j][r]);
        }
    __syncthreads();
    u16* const vt = (u16*)const_cast<void*>(ep);
    const int b = m0 >> 11;
    const int sbase = m0 & 2047;
    #pragma unroll
    for (int it = 0; it < 8; it++) {
      const int fl = it * 256 + tid;
      const int trow = fl >> 4;
      const int tch = fl & 15;
      bf16x8 cv = *(const bf16x8*)&smT[trow * 128 + ((tch * 8) ^ ((trow & 7) << 3))];
      const int dg = n0 - 2048 + trow;
      const int h = dg >> 6, d = dg & 63;
      *(bf16x8*)(vt + (((size_t)(b * 16 + h) * 64 + d) * 2048 + sbase + tch * 8)) = cv;
    }
  } else {
    u16* const smC = smem[0];
    const float s = ((EPI == 0 || EPI == 5) && n0 < ncut) ? scale : 1.0f;
    __syncthreads();
    #pragma unroll
    for (int i = 0; i < 4; i++)
      #pragma unroll
      for (int j = 0; j < 4; j++)
        #pragma unroll
        for (int r = 0; r < 4; r++) {
          const int row = wr * 64 + i * 16 + lk * 4 + r;
          const int col = wc * 64 + j * 16 + lr;
          smC[row * 128 + (col ^ ((row & 7) << 3))] = f2bf(acc[i][j][r] * s);
        }
    __syncthreads();
    if constexpr (EPI == 4) {
      #pragma unroll
      for (int it = 0; it < 4; it++) {
        const int fl = it * 256 + tid;
        const int row = fl >> 3;
        const int ch = fl & 7;
        bf16x8 gvv = *(const bf16x8*)&smC[row * 128 + ((ch ^ (row & 7)) * 8)];
        bf16x8 uvv = *(const bf16x8*)&smC[row * 128 + (((ch + 8) ^ (row & 7)) * 8)];
        bf16x8 ov;
        #pragma unroll
        for (int k = 0; k < 8; k++) {
          float g = bf2f((u16)gvv[k]);
          float u = bf2f((u16)uvv[k]);
          float sg = g / (1.f + __expf(-g));
          ov[k] = (short)f2bf(sg * u);
        }
        *(bf16x8*)((u16*)out + (size_t)(m0 + row) * N + (n0 >> 1) + ch * 8) = ov;
      }
    } else {
      #pragma unroll
      for (int it = 0; it < 8; it++) {
        const int fl = it * 256 + tid;
        const int row = fl >> 4;
        const int ch = fl & 15;
        bf16x8 cv = *(const bf16x8*)&smC[row * 128 + ((ch ^ (row & 7)) * 8)];
        const size_t gidx = (size_t)(m0 + row) * N + n0 + ch * 8;
        *(bf16x8*)((u16*)out + gidx) = cv;
      }
    }
  }
}

// ========== double-buffered 128x128 GEMM (2 blocks/CU) for 2/CU shapes ======
// EPI 1: fp32 = acc + ep_fp32[idx]  (o-proj residual add; down-proj x1+acc)
template <int EPI>
__global__ __launch_bounds__(256, 2)
void gemm128db(const u16* __restrict__ A, const u16* __restrict__ B,
               void* out, const void* ep, int M, int N, int KLOOP, int KS,
               float scale, int ncut) {
  __shared__ u16 sA[2][8192];
  __shared__ u16 sB[2][8192];

  const int tid = threadIdx.x;
  const int lane = tid & 63;
  const int w = tid >> 6;
  const int wr = w >> 1, wc = w & 1;
  const int lr = lane & 15, lk = lane >> 4;

  const int nx = gridDim.x;
  const int nwg = nx * gridDim.y;
  const int flat = blockIdx.y * nx + blockIdx.x;
  const int qq = nwg >> 3, rr = nwg & 7;
  const int xcd = flat & 7, off = flat >> 3;
  const int swz = (xcd < rr ? xcd * (qq + 1) : rr * (qq + 1) + (xcd - rr) * qq) + off;
  const int sr = nx * 8;
  const int g8 = swz / sr, rem = swz % sr;
  const int grp = rem >> 6, r6 = rem & 63;
  const int m0 = (g8 * 8 + (r6 & 7)) * 128;
  const int n0 = (grp * 8 + (r6 >> 3)) * 128;

  f32x4 acc[4][4];
  #pragma unroll
  for (int i = 0; i < 4; i++)
    #pragma unroll
    for (int j = 0; j < 4; j++) acc[i][j] = (f32x4){0.f, 0.f, 0.f, 0.f};

  #define STAGE128(BUF, KT)                                                       \
    _Pragma("unroll")                                                             \
    for (int r = 0; r < 4; r++) {                                                 \
      const int q = r * 256 + tid;                                                \
      const int row = q >> 3;                                                     \
      const int cs = (q & 7) ^ (row & 7);                                         \
      gload_lds16(A + (size_t)(m0 + row) * KS + (KT) + cs * 8,                    \
                  (char*)sA[BUF] + q * 16);                                       \
      gload_lds16(B + (size_t)(n0 + row) * KS + (KT) + cs * 8,                    \
                  (char*)sB[BUF] + q * 16);                                       \
    }

  const int NT = KLOOP >> 6;
  STAGE128(0, 0)
  __syncthreads();

  for (int W = 0; W < NT; ++W) {
    const int buf = W & 1;
    if (W + 1 < NT) { STAGE128(buf ^ 1, (W + 1) << 6) }
    #pragma unroll
    for (int kk = 0; kk < 2; kk++) {
      bf16x8 a_[4], b_[4];
      #pragma unroll
      for (int i = 0; i < 4; i++)
        a_[i] = *(const bf16x8*)&sA[buf][(wr * 64 + i * 16 + lr) * 64 +
                                        (((kk * 4 + lk) ^ (lr & 7)) * 8)];
      #pragma unroll
      for (int j = 0; j < 4; j++)
        b_[j] = *(const bf16x8*)&sB[buf][(wc * 64 + j * 16 + lr) * 64 +
                                         (((kk * 4 + lk) ^ (lr & 7)) * 8)];
      #pragma unroll
      for (int i = 0; i < 4; i++)
        #pragma unroll
        for (int j = 0; j < 4; j++)
          acc[i][j] = __builtin_amdgcn_mfma_f32_16x16x32_bf16(a_[i], b_[j], acc[i][j], 0, 0, 0);
    }
    __syncthreads();
  }
  #undef STAGE128

  #pragma unroll
  for (int i = 0; i < 4; i++)
    #pragma unroll
    for (int j = 0; j < 4; j++)
      #pragma unroll
      for (int r = 0; r < 4; r++) {
        const int grow = m0 + wr * 64 + i * 16 + lk * 4 + r;
        const int gcol = n0 + wc * 64 + j * 16 + lr;
        const size_t idx = (size_t)grow * N + gcol;
        ((float*)out)[idx] = ((const float*)ep)[idx] + acc[i][j][r];
      }
}

// ---------------- causal flash attention v5 ----------------
__global__ __launch_bounds__(256, 4)
void attn_fwd5(const u16* __restrict__ qkv, const u16* __restrict__ vt,
               u16* __restrict__ o) {
  __shared__ u16 sm[9216];
  u16* const smK = sm;
  u16* const smV = sm + 4096;

  const int tid = threadIdx.x;
  const int lane = tid & 63;
  const int w = tid >> 6;
  const int hi = lane >> 5;
  const int ln = lane & 31;

  const int flat = blockIdx.x;
  const int qt = 15 - (flat >> 6);
  const int bh = flat & 63;
  const int b = bh >> 4, h = bh & 15;

  const int qbase = qt * 128;
  const int qw0 = qbase + w * 32;
  const int qglob = qw0 + ln;
  const int nkb = qt * 2 + 2;

  bf16x8 qf[4];
  {
    const u16* qp = qkv + ((size_t)(b * 2048 + qw0 + ln)) * 3072 + h * 64 + hi * 8;
    #pragma unroll
    for (int c = 0; c < 4; c++) qf[c] = *(const bf16x8*)(qp + c * 16);
  }

  f32x16 accO[2];
  #pragma unroll
  for (int i = 0; i < 2; i++)
    #pragma unroll
    for (int r = 0; r < 16; r++) accO[i][r] = 0.f;
  float mrun = -1e30f, lsum = 0.f;

  for (int kb = 0; kb < nkb; kb++) {
    const int kbase = kb * 64;
    __syncthreads();
    #pragma unroll
    for (int r = 0; r < 2; r++) {
      const int cb = w * 128 + r * 64;
      const int ci = cb + lane;
      {
        const int key = ci >> 3, gch = (ci & 7) ^ (key & 7);
        const u16* src = qkv + ((size_t)(b * 2048 + kbase + key)) * 3072 + 1024 + h * 64 + gch * 8;
        gload_lds16(src, (char*)smK + cb * 16);
      }
      {
        const int d = ci >> 3, gch = (ci & 7) ^ (d & 7);
        const u16* src = vt + ((size_t)(bh * 64 + d)) * 2048 + kbase + gch * 8;
        gload_lds16(src, (char*)smV + cb * 16);
      }
    }
    __syncthreads();

    if (kbase <= qw0 + 31) {
      f32x16 st[2];
      #pragma unroll
      for (int kt = 0; kt < 2; kt++) {
        #pragma unroll
        for (int r = 0; r < 16; r++) st[kt][r] = 0.f;
      }
      __builtin_amdgcn_s_setprio(1);
      #pragma unroll
      for (int kt = 0; kt < 2; kt++)
        #pragma unroll
        for (int c = 0; c < 4; c++) {
          const int row = kt * 32 + ln;
          const int sch = (c * 2 + hi) ^ (ln & 7);
          bf16x8 kf = *(const bf16x8*)((const char*)smK + row * 128 + sch * 16);
          st[kt] = __builtin_amdgcn_mfma_f32_32x32x16_bf16(kf, qf[c], st[kt], 0, 0, 0);
        }
      __builtin_amdgcn_s_setprio(0);
      if (kbase + 63 > qw0) {
        #pragma unroll
        for (int kt = 0; kt < 2; kt++)
          #pragma unroll
          for (int r = 0; r < 16; r++) {
            const int kk = kbase + kt * 32 + (r & 3) + 8 * (r >> 2) + 4 * hi;
            if (kk > qglob) st[kt][r] = -1e30f;
          }
      }
      float t16[16];
      #pragma unroll
      for (int i = 0; i < 16; i++) t16[i] = fmaxf(st[0][i], st[1][i]);
      #pragma unroll
      for (int s = 8; s > 0; s >>= 1)
        #pragma unroll
        for (int i = 0; i < 8; i++)
          if (i < s) t16[i] = fmaxf(t16[i], t16[i + s]);
      float pm = t16[0];
      pm = fmaxf(pm, __shfl_xor(pm, 32));
      if (!__all(pm - mrun <= 8.f)) {
        const float mnew = fmaxf(mrun, pm);
        const float alpha = exp2a(mrun - mnew);
        lsum *= alpha;
        accO[0] *= alpha;
        accO[1] *= alpha;
        mrun = mnew;
      }
      #pragma unroll
      for (int kt = 0; kt < 2; kt++)
        #pragma unroll
        for (int r = 0; r < 16; r++) st[kt][r] = exp2a(st[kt][r] - mrun);
      float s16[16];
      #pragma unroll
      for (int i = 0; i < 16; i++) s16[i] = st[0][i] + st[1][i];
      #pragma unroll
      for (int s = 8; s > 0; s >>= 1)
        #pragma unroll
        for (int i = 0; i < 8; i++)
          if (i < s) s16[i] = s16[i] + s16[i + s];
      float ps = s16[0];
      ps += __shfl_xor(ps, 32);
      lsum += ps;

      #pragma unroll
      for (int kt = 0; kt < 2; kt++) {
        u32 pw[8], px[8];
        #pragma unroll
        for (int i = 0; i < 8; i++) pw[i] = cvtpk(st[kt][2 * i], st[kt][2 * i + 1]);
        #pragma unroll
        for (int i = 0; i < 8; i++) px[i] = (u32)__shfl_xor((int)pw[i], 32);
        union { u32 wd[4]; bf16x8 v; } f0, f1;
        f0.wd[0] = hi ? px[2] : pw[0];
        f0.wd[1] = hi ? px[3] : pw[1];
        f0.wd[2] = hi ? pw[2] : px[0];
        f0.wd[3] = hi ? pw[3] : px[1];
        f1.wd[0] = hi ? px[6] : pw[4];
        f1.wd[1] = hi ? px[7] : pw[5];
        f1.wd[2] = hi ? pw[6] : px[4];
        f1.wd[3] = hi ? pw[7] : px[5];
        __builtin_amdgcn_s_setprio(1);
        #pragma unroll
        for (int d0 = 0; d0 < 2; d0++) {
          #pragma unroll
          for (int kc = 0; kc < 2; kc++) {
            const int drow = d0 * 32 + ln;
            const int sch = (kt * 4 + kc * 2 + hi) ^ (ln & 7);
            bf16x8 vf = *(const bf16x8*)((const char*)smV + drow * 128 + sch * 16);
            accO[d0] = __builtin_amdgcn_mfma_f32_32x32x16_bf16(vf, kc ? f1.v : f0.v,
                                                               accO[d0], 0, 0, 0);
          }
        }
        __builtin_amdgcn_s_setprio(0);
      }
    }
  }

  __syncthreads();
  const float inv = 1.0f / lsum;
  #pragma unroll
  for (int d0 = 0; d0 < 2; d0++)
    #pragma unroll
    for (int r = 0; r < 16; r++) {
      const int d = d0 * 32 + (r & 3) + 8 * (r >> 2) + 4 * hi;
      sm[(w * 32 + ln) * 72 + d] = f2bf(accO[d0][r] * inv);
    }
  __syncthreads();
  const int ql = tid >> 1, dh = (tid & 1) * 32;
  const u16* srcp = &sm[ql * 72 + dh];
  u16* dst = o + ((size_t)(b * 2048 + qbase + ql)) * 1024 + h * 64 + dh;
  #pragma unroll
  for (int j = 0; j < 4; j++)
    *(bf16x8*)(dst + j * 8) = *(const bf16x8*)(srcp + j * 8);
}

// ---------------- host ----------------
extern "C" void kernel_launch(void* const* d_in, const int* in_sizes, int n_in,
                              void* d_out, int out_size, void* d_ws, size_t ws_size,
                              hipStream_t stream) {
  const float* x      = (const float*)d_in[0];
  const float* W_q    = (const float*)d_in[1];
  const float* W_k    = (const float*)d_in[2];
  const float* W_v    = (const float*)d_in[3];
  const float* W_o    = (const float*)d_in[4];
  const float* gamma1 = (const float*)d_in[5];
  const float* gamma2 = (const float*)d_in[6];
  const float* W1     = (const float*)d_in[7];
  const float* W2     = (const float*)d_in[8];
  const float* W3     = (const float*)d_in[9];

  char* ws = (char*)d_ws;
  const size_t MB = 1ull << 20;
  u16* qkvw  = (u16*)(ws + 0 * MB);
  u16* Wo_b  = (u16*)(ws + 6 * MB);
  u16* W13   = (u16*)(ws + 8 * MB);
  u16* W2_b  = (u16*)(ws + 24 * MB);
  u16* xn    = (u16*)(ws + 32 * MB);
  u16* qkvb  = (u16*)(ws + 48 * MB);
  u16* attnb = (u16*)(ws + 96 * MB);
  u16* vtb   = (u16*)(ws + 112 * MB);
  u16* hbuf  = (u16*)(ws + 128 * MB);
  float* x1  = (float*)d_out;

  prep_all<<<24576, 256, 0, stream>>>(W_q, W_k, W_v, W_o, W2, W1, W3, x, gamma1,
                                      qkvw, Wo_b, W2_b, W13, xn);

  // QKV (EPI5): Q/K -> qkvb (q pre-scaled, exp2 domain); V -> vtb transposed
  gemm128<5><<<dim3(24, 64), 256, 0, stream>>>(xn, qkvw, qkvb, vtb,
                                               8192, 3072, 1024, 1024,
                                               0.125f * 1.44269504f, 1024);
  attn_fwd5<<<dim3(1024), 256, 0, stream>>>(qkvb, vtb, attnb);
  // o-proj: double-buffered, residual add x -> x1 (d_out)
  gemm128db<1><<<dim3(8, 64), 256, 0, stream>>>(attnb, Wo_b, x1, x,
                                                8192, 1024, 1024, 1024, 1.0f, 0);

  rmsnorm_k<<<8192, 256, 0, stream>>>(x1, gamma2, xn);
  gemm128<4><<<dim3(64, 64), 256, 0, stream>>>(xn, W13, hbuf, nullptr,
                                               8192, 4096, 1024, 1024, 1.0f, 0);
  // down-proj: double-buffered, no split-K, x1 + acc -> d_out (in place)
  gemm128db<1><<<dim3(8, 64), 256, 0, stream>>>(hbuf, W2_b, (float*)d_out,
                                                (const float*)d_out,
                                                8192, 1024, 4096, 4096, 1.0f, 0);
}